// Round 1
// baseline (2603.160 us; speedup 1.0000x reference)
//
#include <hip/hip_runtime.h>
#include <hip/hip_bf16.h>
#include <math.h>

// Problem constants (fixed by setup_inputs)
constexpr int Bc = 2;
constexpr int Sc = 2048;
constexpr int Ec = 1024;
constexpr int Hc = 16;
constexpr int Dc = 64;

// ---------------------------------------------------------------------------
// GEMM + bias: C = A[M,K] @ W[K,N] + bias[N]
// head_layout=1: scatter output (m,n) -> [B,H,S,D] at ((b*H+h)*S+s)*D+d
// Tile 64x64, BK=16, 256 threads, 4x4 per thread. fp32 baseline.
// ---------------------------------------------------------------------------
__global__ __launch_bounds__(256) void gemm_bias_kernel(
    const float* __restrict__ A, const float* __restrict__ W,
    const float* __restrict__ bias, float* __restrict__ C,
    int M, int N, int K, int head_layout)
{
    __shared__ float As[64][17];   // +1 pad
    __shared__ float Bs[16][68];   // +4 pad (keeps float4 alignment)
    const int t  = threadIdx.x;
    const int tx = t & 15, ty = t >> 4;
    const int row0 = blockIdx.y * 64;
    const int col0 = blockIdx.x * 64;
    float acc[4][4] = {};

    for (int k0 = 0; k0 < K; k0 += 16) {
        {   // A tile 64x16: thread -> row t>>2, 4 consecutive k
            int r = t >> 2, c = (t & 3) * 4;
            float4 av = *(const float4*)&A[(size_t)(row0 + r) * K + k0 + c];
            As[r][c] = av.x; As[r][c + 1] = av.y; As[r][c + 2] = av.z; As[r][c + 3] = av.w;
        }
        {   // B tile 16x64: thread -> row t>>4, 4 consecutive n
            int r = t >> 4, c = (t & 15) * 4;
            float4 bv = *(const float4*)&W[(size_t)(k0 + r) * N + col0 + c];
            *(float4*)&Bs[r][c] = bv;
        }
        __syncthreads();
#pragma unroll
        for (int kk = 0; kk < 16; ++kk) {
            float a0 = As[ty * 4 + 0][kk];
            float a1 = As[ty * 4 + 1][kk];
            float a2 = As[ty * 4 + 2][kk];
            float a3 = As[ty * 4 + 3][kk];
            float4 b = *(const float4*)&Bs[kk][tx * 4];
            acc[0][0] += a0 * b.x; acc[0][1] += a0 * b.y; acc[0][2] += a0 * b.z; acc[0][3] += a0 * b.w;
            acc[1][0] += a1 * b.x; acc[1][1] += a1 * b.y; acc[1][2] += a1 * b.z; acc[1][3] += a1 * b.w;
            acc[2][0] += a2 * b.x; acc[2][1] += a2 * b.y; acc[2][2] += a2 * b.z; acc[2][3] += a2 * b.w;
            acc[3][0] += a3 * b.x; acc[3][1] += a3 * b.y; acc[3][2] += a3 * b.z; acc[3][3] += a3 * b.w;
        }
        __syncthreads();
    }

#pragma unroll
    for (int i = 0; i < 4; ++i) {
        int m = row0 + ty * 4 + i;
#pragma unroll
        for (int j = 0; j < 4; ++j) {
            int n = col0 + tx * 4 + j;
            float v = acc[i][j] + bias[n];
            if (head_layout) {
                int b = m >> 11, s = m & (Sc - 1);
                int h = n >> 6,  d = n & (Dc - 1);
                C[(((size_t)b * Hc + h) * Sc + s) * Dc + d] = v;
            } else {
                C[(size_t)m * N + n] = v;
            }
        }
    }
}

// ---------------------------------------------------------------------------
// Flash attention, fp32 baseline.
// grid (B*H, S/64); 64 threads (1 wave). Each thread owns one query row.
// K/V tiles of 64 rows staged in LDS (coalesced loads, broadcast reads).
// Online softmax in chunks of 8 keys (static register indices only).
// Output written to Y in [B,S,E] layout for the out-projection GEMM.
// ---------------------------------------------------------------------------
__global__ __launch_bounds__(64) void attn_kernel(
    const float* __restrict__ Q, const float* __restrict__ K,
    const float* __restrict__ V, float* __restrict__ Y)
{
    __shared__ float Ks[64][68];
    __shared__ float Vs[64][68];
    const int lane = threadIdx.x;
    const int bh = blockIdx.x;          // 0..B*H-1
    const int qt = blockIdx.y;          // 0..S/64-1
    const int r  = qt * 64 + lane;

    const float4* qrow = (const float4*)(Q + ((size_t)bh * Sc + r) * Dc);
    float4 q4[16];
#pragma unroll
    for (int i = 0; i < 16; ++i) q4[i] = qrow[i];

    float4 o4[16];
#pragma unroll
    for (int i = 0; i < 16; ++i) o4[i] = make_float4(0.f, 0.f, 0.f, 0.f);
    float mrun = -INFINITY, lrun = 0.f;
    const float scale = 0.125f;   // 1/sqrt(64)

    for (int kt = 0; kt < Sc / 64; ++kt) {
        // tile is 64*64 contiguous floats -> fully coalesced float4 loads
        const float4* ksrc = (const float4*)(K + ((size_t)bh * Sc + kt * 64) * Dc);
        const float4* vsrc = (const float4*)(V + ((size_t)bh * Sc + kt * 64) * Dc);
#pragma unroll
        for (int i = 0; i < 16; ++i) {
            int f = i * 64 + lane;             // float4 flat index 0..1023
            int row = f >> 4, c4 = (f & 15) << 2;
            *(float4*)&Ks[row][c4] = ksrc[f];
            *(float4*)&Vs[row][c4] = vsrc[f];
        }
        __syncthreads();

#pragma unroll 1
        for (int c = 0; c < 8; ++c) {          // 8 chunks of 8 keys
            float sarr[8];
            float cmax = -INFINITY;
#pragma unroll
            for (int j = 0; j < 8; ++j) {
                const float4* kr = (const float4*)&Ks[c * 8 + j][0];
                float s = 0.f;
#pragma unroll
                for (int i = 0; i < 16; ++i) {
                    float4 kv = kr[i];
                    s += q4[i].x * kv.x + q4[i].y * kv.y + q4[i].z * kv.z + q4[i].w * kv.w;
                }
                s *= scale;
                sarr[j] = s;
                cmax = fmaxf(cmax, s);
            }
            float mnew = fmaxf(mrun, cmax);
            float corr = __expf(mrun - mnew);   // exp(-inf)=0 on first chunk
            lrun *= corr;
#pragma unroll
            for (int i = 0; i < 16; ++i) {
                o4[i].x *= corr; o4[i].y *= corr; o4[i].z *= corr; o4[i].w *= corr;
            }
#pragma unroll
            for (int j = 0; j < 8; ++j) {
                float p = __expf(sarr[j] - mnew);
                lrun += p;
                const float4* vr = (const float4*)&Vs[c * 8 + j][0];
#pragma unroll
                for (int i = 0; i < 16; ++i) {
                    float4 vv = vr[i];
                    o4[i].x += p * vv.x; o4[i].y += p * vv.y;
                    o4[i].z += p * vv.z; o4[i].w += p * vv.w;
                }
            }
            mrun = mnew;
        }
        __syncthreads();
    }

    float inv = 1.f / lrun;
    const int b = bh / Hc, h = bh % Hc;
    float4* yrow = (float4*)(Y + ((size_t)b * Sc + r) * Ec + h * Dc);
#pragma unroll
    for (int i = 0; i < 16; ++i) {
        float4 o = o4[i];
        o.x *= inv; o.y *= inv; o.z *= inv; o.w *= inv;
        yrow[i] = o;
    }
}

// ---------------------------------------------------------------------------
// LayerNorm, torch semantics: (x - mean) / (std + eps) * gain + beta,
// std with Bessel correction (ddof=1). One block (256 threads) per row.
// ---------------------------------------------------------------------------
__global__ __launch_bounds__(256) void ln_kernel(
    const float* __restrict__ Z, const float* __restrict__ gain,
    const float* __restrict__ beta, float* __restrict__ out)
{
    __shared__ float red0[4];
    __shared__ float red1[4];
    const int row = blockIdx.x;
    const int t = threadIdx.x;
    const float4* z4 = (const float4*)(Z + (size_t)row * Ec);
    float4 v = z4[t];

    float s = v.x + v.y + v.z + v.w;
#pragma unroll
    for (int off = 32; off > 0; off >>= 1) s += __shfl_down(s, off);
    if ((t & 63) == 0) red0[t >> 6] = s;
    __syncthreads();
    float mean = (red0[0] + red0[1] + red0[2] + red0[3]) * (1.0f / Ec);

    float dx = v.x - mean; float vs = dx * dx;
    dx = v.y - mean; vs += dx * dx;
    dx = v.z - mean; vs += dx * dx;
    dx = v.w - mean; vs += dx * dx;
#pragma unroll
    for (int off = 32; off > 0; off >>= 1) vs += __shfl_down(vs, off);
    if ((t & 63) == 0) red1[t >> 6] = vs;
    __syncthreads();
    float var = (red1[0] + red1[1] + red1[2] + red1[3]) * (1.0f / (Ec - 1));
    float inv = 1.0f / (sqrtf(var) + 1e-6f);

    float4 g = ((const float4*)gain)[t];
    float4 bb = ((const float4*)beta)[t];
    float4 o;
    o.x = (v.x - mean) * inv * g.x + bb.x;
    o.y = (v.y - mean) * inv * g.y + bb.y;
    o.z = (v.z - mean) * inv * g.z + bb.z;
    o.w = (v.w - mean) * inv * g.w + bb.w;
    ((float4*)(out + (size_t)row * Ec))[t] = o;
}

// ---------------------------------------------------------------------------
extern "C" void kernel_launch(void* const* d_in, const int* in_sizes, int n_in,
                              void* d_out, int out_size, void* d_ws, size_t ws_size,
                              hipStream_t stream)
{
    const float* x    = (const float*)d_in[0];
    const float* Wq   = (const float*)d_in[1];
    const float* bq   = (const float*)d_in[2];
    const float* Wk   = (const float*)d_in[3];
    const float* bk   = (const float*)d_in[4];
    const float* Wv   = (const float*)d_in[5];
    const float* bv   = (const float*)d_in[6];
    const float* Wp   = (const float*)d_in[7];
    const float* bp   = (const float*)d_in[8];
    const float* gain = (const float*)d_in[9];
    const float* beta = (const float*)d_in[10];

    float* ws = (float*)d_ws;
    const size_t BSE = (size_t)Bc * Sc * Ec;   // 4,194,304 floats
    float* q = ws;             // [B,H,S,D]
    float* k = ws + BSE;       // [B,H,S,D]
    float* v = ws + 2 * BSE;   // [B,H,S,D]
    float* y = ws + 3 * BSE;   // [B,S,E]
    float* z = q;              // q is dead after attention; reuse for proj out

    const int M = Bc * Sc;     // 4096
    dim3 gemm_grid(Ec / 64, M / 64);

    gemm_bias_kernel<<<gemm_grid, 256, 0, stream>>>(x, Wq, bq, q, M, Ec, Ec, 1);
    gemm_bias_kernel<<<gemm_grid, 256, 0, stream>>>(x, Wk, bk, k, M, Ec, Ec, 1);
    gemm_bias_kernel<<<gemm_grid, 256, 0, stream>>>(x, Wv, bv, v, M, Ec, Ec, 1);

    dim3 attn_grid(Bc * Hc, Sc / 64);
    attn_kernel<<<attn_grid, 64, 0, stream>>>(q, k, v, y);

    gemm_bias_kernel<<<gemm_grid, 256, 0, stream>>>(y, Wp, bp, z, M, Ec, Ec, 0);

    ln_kernel<<<M, 256, 0, stream>>>(z, gain, beta, (float*)d_out);
}

// Round 2
// 763.105 us; speedup vs baseline: 3.4113x; 3.4113x over previous
//
#include <hip/hip_runtime.h>
#include <hip/hip_bf16.h>
#include <math.h>

// Problem constants (fixed by setup_inputs)
constexpr int Bc = 2;
constexpr int Sc = 2048;
constexpr int Ec = 1024;
constexpr int Hc = 16;
constexpr int Dc = 64;

typedef __attribute__((ext_vector_type(8))) short short8;
typedef __attribute__((ext_vector_type(4))) float f32x4;
typedef __attribute__((ext_vector_type(4))) unsigned short ushort4v;

__device__ inline unsigned short f2bf(float x) {
    __hip_bfloat16 h = __float2bfloat16(x);
    return *reinterpret_cast<unsigned short*>(&h);
}

__device__ inline f32x4 mfma16(short8 a, short8 b, f32x4 c) {
    return __builtin_amdgcn_mfma_f32_16x16x32_bf16(a, b, c, 0, 0, 0);
}

// ---------------------------------------------------------------------------
// GEMM + bias: C = A[M,K] @ W[K,N] + bias[N]
// mode 0: fp32 row-major [M,N] -> Cf
// mode 1: bf16 head layout [B,H,S,D]  (for Q, K)
// mode 2: bf16 transposed head layout [B*H, D, S]  (for V)
// Tile 64x64, BK=16, 256 threads, 4x4 per thread. fp32 compute.
// ---------------------------------------------------------------------------
__global__ __launch_bounds__(256) void gemm_bias_kernel(
    const float* __restrict__ A, const float* __restrict__ W,
    const float* __restrict__ bias, float* __restrict__ Cf,
    __hip_bfloat16* __restrict__ Cb,
    int M, int N, int K, int mode)
{
    __shared__ float As[64][17];
    __shared__ float Bs[16][68];
    const int t  = threadIdx.x;
    const int tx = t & 15, ty = t >> 4;
    const int row0 = blockIdx.y * 64;
    const int col0 = blockIdx.x * 64;
    float acc[4][4] = {};

    for (int k0 = 0; k0 < K; k0 += 16) {
        {
            int r = t >> 2, c = (t & 3) * 4;
            float4 av = *(const float4*)&A[(size_t)(row0 + r) * K + k0 + c];
            As[r][c] = av.x; As[r][c + 1] = av.y; As[r][c + 2] = av.z; As[r][c + 3] = av.w;
        }
        {
            int r = t >> 4, c = (t & 15) * 4;
            float4 bv = *(const float4*)&W[(size_t)(k0 + r) * N + col0 + c];
            *(float4*)&Bs[r][c] = bv;
        }
        __syncthreads();
#pragma unroll
        for (int kk = 0; kk < 16; ++kk) {
            float a0 = As[ty * 4 + 0][kk];
            float a1 = As[ty * 4 + 1][kk];
            float a2 = As[ty * 4 + 2][kk];
            float a3 = As[ty * 4 + 3][kk];
            float4 b = *(const float4*)&Bs[kk][tx * 4];
            acc[0][0] += a0 * b.x; acc[0][1] += a0 * b.y; acc[0][2] += a0 * b.z; acc[0][3] += a0 * b.w;
            acc[1][0] += a1 * b.x; acc[1][1] += a1 * b.y; acc[1][2] += a1 * b.z; acc[1][3] += a1 * b.w;
            acc[2][0] += a2 * b.x; acc[2][1] += a2 * b.y; acc[2][2] += a2 * b.z; acc[2][3] += a2 * b.w;
            acc[3][0] += a3 * b.x; acc[3][1] += a3 * b.y; acc[3][2] += a3 * b.z; acc[3][3] += a3 * b.w;
        }
        __syncthreads();
    }

    const int n0 = col0 + tx * 4;
    if (mode == 0) {
#pragma unroll
        for (int i = 0; i < 4; ++i) {
            int m = row0 + ty * 4 + i;
            float4 o;
            o.x = acc[i][0] + bias[n0 + 0];
            o.y = acc[i][1] + bias[n0 + 1];
            o.z = acc[i][2] + bias[n0 + 2];
            o.w = acc[i][3] + bias[n0 + 3];
            *(float4*)&Cf[(size_t)m * N + n0] = o;
        }
    } else if (mode == 1) {
        // bf16 [B,H,S,D]: 4 consecutive d per store
        int h = n0 >> 6, d0 = n0 & (Dc - 1);
#pragma unroll
        for (int i = 0; i < 4; ++i) {
            int m = row0 + ty * 4 + i;
            int b = m >> 11, s = m & (Sc - 1);
            ushort4v pk;
            pk[0] = f2bf(acc[i][0] + bias[n0 + 0]);
            pk[1] = f2bf(acc[i][1] + bias[n0 + 1]);
            pk[2] = f2bf(acc[i][2] + bias[n0 + 2]);
            pk[3] = f2bf(acc[i][3] + bias[n0 + 3]);
            *(ushort4v*)&Cb[(((size_t)b * Hc + h) * Sc + s) * Dc + d0] = pk;
        }
    } else {
        // bf16 [B*H, D, S] transposed: 4 consecutive s per store
        int m0 = row0 + ty * 4;
        int b = m0 >> 11, s0 = m0 & (Sc - 1);
#pragma unroll
        for (int j = 0; j < 4; ++j) {
            int n = n0 + j;
            int h = n >> 6, d = n & (Dc - 1);
            float bi = bias[n];
            ushort4v pk;
            pk[0] = f2bf(acc[0][j] + bi);
            pk[1] = f2bf(acc[1][j] + bi);
            pk[2] = f2bf(acc[2][j] + bi);
            pk[3] = f2bf(acc[3][j] + bi);
            *(ushort4v*)&Cb[((size_t)(b * Hc + h) * Dc + d) * Sc + s0] = pk;
        }
    }
}

// ---------------------------------------------------------------------------
// Flash attention, bf16 MFMA (16x16x32).
// grid (B*H, S/64); 256 threads = 4 waves; each wave owns 16 Q-rows.
// Q: bf16 [bh,S,D]; K: bf16 [bh,S,D]; V: bf16 TRANSPOSED [bh,D,S].
// KV tile = 64 keys staged in LDS (K row-major padded, V d-major padded).
// Scores C-layout: col=key=lane&15, row=q=(lane>>4)*4+reg. P goes through a
// small per-wave LDS buffer to reach MFMA A-layout.
// Output Y fp32 [B,S,E].
// ---------------------------------------------------------------------------
__global__ __launch_bounds__(256) void attn_mfma_kernel(
    const __hip_bfloat16* __restrict__ Q, const __hip_bfloat16* __restrict__ K,
    const __hip_bfloat16* __restrict__ Vt, float* __restrict__ Y)
{
    __shared__ __align__(16) unsigned short Ks[64][72];   // [key][d]
    __shared__ __align__(16) unsigned short Vs[64][72];   // [d][key]
    __shared__ __align__(16) unsigned short Ps[4][16][40]; // per-wave [q][key]

    const int tid  = threadIdx.x;
    const int lane = tid & 63, wid = tid >> 6;
    const int g = lane >> 4, c16 = lane & 15;
    const int bh = blockIdx.x;
    const int q0 = blockIdx.y * 64;
    const size_t base = (size_t)bh * Sc * Dc;   // same size for [S,D] and [D,S]

    // Q fragments for this wave's 16 rows (A-layout: row=c16, k=g*8+j)
    const unsigned short* Qp = (const unsigned short*)Q + base + (size_t)(q0 + wid * 16 + c16) * Dc;
    short8 aq0 = *(const short8*)(Qp + g * 8);
    short8 aq1 = *(const short8*)(Qp + 32 + g * 8);

    f32x4 o[4] = {};                   // col=d0+c16, row=q=4g+r
    float mrun[4], lsum[4];
#pragma unroll
    for (int r = 0; r < 4; ++r) { mrun[r] = -INFINITY; lsum[r] = 0.f; }

    const float scale = 0.125f;  // 1/sqrt(64)

    for (int kt = 0; kt < Sc / 64; ++kt) {
        __syncthreads();
        {   // stage K tile: thread -> key=t>>2, dblk=(t&3)*16
            int key = tid >> 2, db = (tid & 3) * 16;
            const unsigned short* ks = (const unsigned short*)K + base + (size_t)(kt * 64 + key) * Dc + db;
            *(short8*)&Ks[key][db]     = *(const short8*)ks;
            *(short8*)&Ks[key][db + 8] = *(const short8*)(ks + 8);
            // stage V tile (already transposed in global): thread -> d=t>>2, keyblk=(t&3)*16
            int d = tid >> 2, kb = (tid & 3) * 16;
            const unsigned short* vs = (const unsigned short*)Vt + base + (size_t)d * Sc + kt * 64 + kb;
            *(short8*)&Vs[d][kb]     = *(const short8*)vs;
            *(short8*)&Vs[d][kb + 8] = *(const short8*)(vs + 8);
        }
        __syncthreads();

#pragma unroll
        for (int kc = 0; kc < 2; ++kc) {   // two 32-key chunks
            // QK^T: two 16-key column tiles, K-dim 64 = 2 MFMAs each
            f32x4 z0 = {}, z1 = {};
            short8 b00 = *(const short8*)&Ks[kc * 32 + c16][g * 8];
            short8 b01 = *(const short8*)&Ks[kc * 32 + c16][32 + g * 8];
            f32x4 c0 = mfma16(aq0, b00, z0);
            c0 = mfma16(aq1, b01, c0);
            short8 b10 = *(const short8*)&Ks[kc * 32 + 16 + c16][g * 8];
            short8 b11 = *(const short8*)&Ks[kc * 32 + 16 + c16][32 + g * 8];
            f32x4 c1 = mfma16(aq0, b10, z1);
            c1 = mfma16(aq1, b11, c1);

            // online softmax (rows q=4g+r live in 16-lane groups)
            float corr[4];
#pragma unroll
            for (int r = 0; r < 4; ++r) {
                float s0 = c0[r] * scale, s1 = c1[r] * scale;
                float tm = fmaxf(s0, s1);
                tm = fmaxf(tm, __shfl_xor(tm, 1));
                tm = fmaxf(tm, __shfl_xor(tm, 2));
                tm = fmaxf(tm, __shfl_xor(tm, 4));
                tm = fmaxf(tm, __shfl_xor(tm, 8));
                float mnew = fmaxf(mrun[r], tm);
                corr[r] = __expf(mrun[r] - mnew);
                float p0 = __expf(s0 - mnew);
                float p1 = __expf(s1 - mnew);
                float ps = p0 + p1;
                ps += __shfl_xor(ps, 1);
                ps += __shfl_xor(ps, 2);
                ps += __shfl_xor(ps, 4);
                ps += __shfl_xor(ps, 8);
                lsum[r] = lsum[r] * corr[r] + ps;
                mrun[r] = mnew;
                Ps[wid][g * 4 + r][c16]      = f2bf(p0);
                Ps[wid][g * 4 + r][16 + c16] = f2bf(p1);
            }
#pragma unroll
            for (int dt = 0; dt < 4; ++dt) {
#pragma unroll
                for (int r = 0; r < 4; ++r) o[dt][r] *= corr[r];
            }
            // make P writes visible to same-wave lanes before A-frag read
            asm volatile("s_waitcnt lgkmcnt(0)" ::: "memory");
            short8 ap = *(const short8*)&Ps[wid][c16][g * 8];
            // PV: 4 d-tiles, K-dim = 32 keys
#pragma unroll
            for (int dt = 0; dt < 4; ++dt) {
                short8 bv = *(const short8*)&Vs[dt * 16 + c16][kc * 32 + g * 8];
                o[dt] = mfma16(ap, bv, o[dt]);
            }
        }
    }

    // epilogue: Y[b, q, h*64 + d] fp32
    const int b = bh >> 4, h = bh & (Hc - 1);
#pragma unroll
    for (int r = 0; r < 4; ++r) {
        float inv = 1.f / lsum[r];
        int qg = q0 + wid * 16 + g * 4 + r;
        float* yrow = Y + ((size_t)b * Sc + qg) * Ec + h * Dc;
#pragma unroll
        for (int dt = 0; dt < 4; ++dt)
            yrow[dt * 16 + c16] = o[dt][r] * inv;
    }
}

// ---------------------------------------------------------------------------
// LayerNorm, torch semantics: (x - mean) / (std + eps) * gain + beta, ddof=1.
// ---------------------------------------------------------------------------
__global__ __launch_bounds__(256) void ln_kernel(
    const float* __restrict__ Z, const float* __restrict__ gain,
    const float* __restrict__ beta, float* __restrict__ out)
{
    __shared__ float red0[4];
    __shared__ float red1[4];
    const int row = blockIdx.x;
    const int t = threadIdx.x;
    const float4* z4 = (const float4*)(Z + (size_t)row * Ec);
    float4 v = z4[t];

    float s = v.x + v.y + v.z + v.w;
#pragma unroll
    for (int off = 32; off > 0; off >>= 1) s += __shfl_down(s, off);
    if ((t & 63) == 0) red0[t >> 6] = s;
    __syncthreads();
    float mean = (red0[0] + red0[1] + red0[2] + red0[3]) * (1.0f / Ec);

    float dx = v.x - mean; float vs = dx * dx;
    dx = v.y - mean; vs += dx * dx;
    dx = v.z - mean; vs += dx * dx;
    dx = v.w - mean; vs += dx * dx;
#pragma unroll
    for (int off = 32; off > 0; off >>= 1) vs += __shfl_down(vs, off);
    if ((t & 63) == 0) red1[t >> 6] = vs;
    __syncthreads();
    float var = (red1[0] + red1[1] + red1[2] + red1[3]) * (1.0f / (Ec - 1));
    float inv = 1.0f / (sqrtf(var) + 1e-6f);

    float4 g = ((const float4*)gain)[t];
    float4 bb = ((const float4*)beta)[t];
    float4 o;
    o.x = (v.x - mean) * inv * g.x + bb.x;
    o.y = (v.y - mean) * inv * g.y + bb.y;
    o.z = (v.z - mean) * inv * g.z + bb.z;
    o.w = (v.w - mean) * inv * g.w + bb.w;
    ((float4*)(out + (size_t)row * Ec))[t] = o;
}

// ---------------------------------------------------------------------------
extern "C" void kernel_launch(void* const* d_in, const int* in_sizes, int n_in,
                              void* d_out, int out_size, void* d_ws, size_t ws_size,
                              hipStream_t stream)
{
    const float* x    = (const float*)d_in[0];
    const float* Wq   = (const float*)d_in[1];
    const float* bq   = (const float*)d_in[2];
    const float* Wk   = (const float*)d_in[3];
    const float* bk   = (const float*)d_in[4];
    const float* Wv   = (const float*)d_in[5];
    const float* bv   = (const float*)d_in[6];
    const float* Wp   = (const float*)d_in[7];
    const float* bp   = (const float*)d_in[8];
    const float* gain = (const float*)d_in[9];
    const float* beta = (const float*)d_in[10];

    const size_t BHSD = (size_t)Bc * Hc * Sc * Dc;  // 4,194,304 elems
    const size_t BSE  = (size_t)Bc * Sc * Ec;
    __hip_bfloat16* qb = (__hip_bfloat16*)d_ws;          //  8 MB
    __hip_bfloat16* kb = qb + BHSD;                      //  8 MB
    __hip_bfloat16* vb = kb + BHSD;                      //  8 MB (transposed)
    float* y = (float*)(vb + BHSD);                      // 16 MB
    float* z = y + BSE;                                  // 16 MB

    const int M = Bc * Sc;     // 4096
    dim3 gemm_grid(Ec / 64, M / 64);

    gemm_bias_kernel<<<gemm_grid, 256, 0, stream>>>(x, Wq, bq, nullptr, qb, M, Ec, Ec, 1);
    gemm_bias_kernel<<<gemm_grid, 256, 0, stream>>>(x, Wk, bk, nullptr, kb, M, Ec, Ec, 1);
    gemm_bias_kernel<<<gemm_grid, 256, 0, stream>>>(x, Wv, bv, nullptr, vb, M, Ec, Ec, 2);

    dim3 attn_grid(Bc * Hc, Sc / 64);
    attn_mfma_kernel<<<attn_grid, 256, 0, stream>>>(qb, kb, vb, y);

    gemm_bias_kernel<<<gemm_grid, 256, 0, stream>>>(y, Wp, bp, z, nullptr, M, Ec, Ec, 0);

    ln_kernel<<<M, 256, 0, stream>>>(z, gain, beta, (float*)d_out);
}

// Round 3
// 252.572 us; speedup vs baseline: 10.3066x; 3.0213x over previous
//
#include <hip/hip_runtime.h>
#include <hip/hip_bf16.h>
#include <math.h>

// Problem constants (fixed by setup_inputs)
constexpr int Bc = 2;
constexpr int Sc = 2048;
constexpr int Ec = 1024;
constexpr int Hc = 16;
constexpr int Dc = 64;

typedef __attribute__((ext_vector_type(8))) short short8;
typedef __attribute__((ext_vector_type(4))) float f32x4;

__device__ inline unsigned short f2bf(float x) {
    __hip_bfloat16 h = __float2bfloat16(x);
    return *reinterpret_cast<unsigned short*>(&h);
}

__device__ inline f32x4 mfma16(short8 a, short8 b, f32x4 c) {
    return __builtin_amdgcn_mfma_f32_16x16x32_bf16(a, b, c, 0, 0, 0);
}

__device__ inline void gload_lds16(const unsigned short* gsrc, unsigned short* ldst) {
    __builtin_amdgcn_global_load_lds(
        (const __attribute__((address_space(1))) unsigned int*)(const void*)gsrc,
        (__attribute__((address_space(3))) unsigned int*)(void*)ldst,
        16, 0, 0);
}

// ---------------------------------------------------------------------------
// x fp32 [M,K] -> bf16 [M,K]. 8 elems/thread.
// ---------------------------------------------------------------------------
__global__ __launch_bounds__(256) void convert_x_kernel(
    const float* __restrict__ X, unsigned short* __restrict__ Xb, int total8)
{
    int i = blockIdx.x * 256 + threadIdx.x;
    if (i >= total8) return;
    const float4* src = (const float4*)(X + (size_t)i * 8);
    float4 a = src[0], b = src[1];
    short8 o;
    o[0] = f2bf(a.x); o[1] = f2bf(a.y); o[2] = f2bf(a.z); o[3] = f2bf(a.w);
    o[4] = f2bf(b.x); o[5] = f2bf(b.y); o[6] = f2bf(b.z); o[7] = f2bf(b.w);
    *(short8*)(Xb + (size_t)i * 8) = o;
}

// ---------------------------------------------------------------------------
// W fp32 [K,N] -> Wt bf16 [N,K]; blockIdx.z selects which of 4 weights.
// 64x64 LDS tile transpose.
// ---------------------------------------------------------------------------
__global__ __launch_bounds__(256) void transpose_w_kernel(
    const float* __restrict__ W0, const float* __restrict__ W1,
    const float* __restrict__ W2, const float* __restrict__ W3,
    unsigned short* __restrict__ T0, unsigned short* __restrict__ T1,
    unsigned short* __restrict__ T2, unsigned short* __restrict__ T3)
{
    __shared__ unsigned short Ls[64][72];
    const float* W; unsigned short* T;
    switch (blockIdx.z) {
        case 0: W = W0; T = T0; break;
        case 1: W = W1; T = T1; break;
        case 2: W = W2; T = T2; break;
        default: W = W3; T = T3; break;
    }
    const int n0 = blockIdx.x * 64, k0 = blockIdx.y * 64;
    const int t = threadIdx.x;
    {   // read 64(k) x 64(n), coalesced along n
        int k = t >> 2, nb = (t & 3) * 16;
        const float* src = W + (size_t)(k0 + k) * Ec + n0 + nb;
#pragma unroll
        for (int j = 0; j < 16; ++j) Ls[k][nb + j] = f2bf(src[j]);
    }
    __syncthreads();
    {   // write transposed, coalesced along k
        int n = t >> 2, kb = (t & 3) * 16;
        short8 o0, o1;
#pragma unroll
        for (int j = 0; j < 8; ++j) { o0[j] = Ls[kb + j][n]; o1[j] = Ls[kb + 8 + j][n]; }
        unsigned short* dst = T + (size_t)(n0 + n) * Ec + k0 + kb;
        *(short8*)dst = o0;
        *(short8*)(dst + 8) = o1;
    }
}

// ---------------------------------------------------------------------------
// V bf16 [B,H,S,D] -> Vt bf16 [B*H, D, S]. 64x64 LDS tile transpose.
// grid (B*H, S/64).
// ---------------------------------------------------------------------------
__global__ __launch_bounds__(256) void transpose_v_kernel(
    const unsigned short* __restrict__ Vb, unsigned short* __restrict__ Vt)
{
    __shared__ unsigned short Ls[64][72];
    const int bh = blockIdx.x, st = blockIdx.y;
    const int t = threadIdx.x;
    {
        int s = t >> 2, db = (t & 3) * 16;
        const unsigned short* src = Vb + ((size_t)bh * Sc + st * 64 + s) * Dc + db;
        *(short8*)&Ls[s][db]     = *(const short8*)src;
        *(short8*)&Ls[s][db + 8] = *(const short8*)(src + 8);
    }
    __syncthreads();
    {
        int d = t >> 2, sb = (t & 3) * 16;
        short8 o0, o1;
#pragma unroll
        for (int j = 0; j < 8; ++j) { o0[j] = Ls[sb + j][d]; o1[j] = Ls[sb + 8 + j][d]; }
        unsigned short* dst = Vt + ((size_t)bh * Dc + d) * Sc + st * 64 + sb;
        *(short8*)dst = o0;
        *(short8*)(dst + 8) = o1;
    }
}

// ---------------------------------------------------------------------------
// bf16 MFMA GEMM: C = A[M,K]bf16 @ Bt[N,K]bf16^T + bias.
// BM=128 BN=64 BK=64, 256 threads (4 waves 2x2), double-buffered LDS,
// global_load_lds w=16, XOR-swizzled LDS (pre-swizzled global source).
// mode 0: fp32 [M,N].  mode 1: bf16 [B,H,S,D] head scatter.
// ---------------------------------------------------------------------------
constexpr int BM = 128, BN = 64, BK = 64;

__global__ __launch_bounds__(256) void gemm_mfma_kernel(
    const unsigned short* __restrict__ A, const unsigned short* __restrict__ Bt,
    const float* __restrict__ bias, float* __restrict__ Cf,
    unsigned short* __restrict__ Cb, int M, int N, int K, int mode)
{
    __shared__ unsigned short lds[2][BM * BK + BN * BK];   // 48 KB
    const int tid = threadIdx.x, lane = tid & 63, wid = tid >> 6;
    const int c16 = lane & 15, g = lane >> 4;
    const int wr = wid >> 1, wc = wid & 1;
    const int row0 = blockIdx.y * BM, col0 = blockIdx.x * BN;

    // staging: per-lane swizzled global source (rule 21: linear LDS dest,
    // inverse-swizzled source, swizzled read)
    const int rsub = lane >> 3;                    // row within 8-row chunk
    const int colE = ((lane & 7) ^ rsub) * 8;      // source k-offset (elems)

    f32x4 acc[4][2] = {};

    auto stage = [&](int buf, int k0) {
        unsigned short* Ab = &lds[buf][0];
        unsigned short* Bb = &lds[buf][BM * BK];
#pragma unroll
        for (int i = 0; i < 6; ++i) {
            int c = wid * 6 + i;                   // 24 chunks: 16 A + 8 B
            if (c < 16) {
                const unsigned short* src = A + (size_t)(row0 + c * 8 + rsub) * K + k0 + colE;
                gload_lds16(src, Ab + c * 512);
            } else {
                int c2 = c - 16;
                const unsigned short* src = Bt + (size_t)(col0 + c2 * 8 + rsub) * K + k0 + colE;
                gload_lds16(src, Bb + c2 * 512);
            }
        }
    };

    stage(0, 0);
    __syncthreads();
    int cur = 0;
    const int NT = K / BK;
    for (int t = 0; t < NT; ++t) {
        if (t + 1 < NT) stage(cur ^ 1, (t + 1) * BK);
        const unsigned short* Ab = &lds[cur][0];
        const unsigned short* Bb = &lds[cur][BM * BK];
#pragma unroll
        for (int kk = 0; kk < 2; ++kk) {
            const int cb = ((kk * 64 + g * 16) ^ ((c16 & 7) << 4)) >> 1;  // elem offset
            short8 af[4], bfr[2];
#pragma unroll
            for (int m = 0; m < 4; ++m) {
                int row = wr * 64 + m * 16 + c16;
                af[m] = *(const short8*)(Ab + row * BK + cb);
            }
#pragma unroll
            for (int n = 0; n < 2; ++n) {
                int row = wc * 32 + n * 16 + c16;
                bfr[n] = *(const short8*)(Bb + row * BK + cb);
            }
#pragma unroll
            for (int m = 0; m < 4; ++m)
#pragma unroll
                for (int n = 0; n < 2; ++n)
                    acc[m][n] = mfma16(af[m], bfr[n], acc[m][n]);
        }
        __syncthreads();
        cur ^= 1;
    }

    // epilogue: C/D layout col=c16, row=g*4+r (verified m89/m91)
#pragma unroll
    for (int m = 0; m < 4; ++m) {
#pragma unroll
        for (int n = 0; n < 2; ++n) {
            int gc = col0 + wc * 32 + n * 16 + c16;
            float bi = bias[gc];
#pragma unroll
            for (int r = 0; r < 4; ++r) {
                int gr = row0 + wr * 64 + m * 16 + g * 4 + r;
                float v = acc[m][n][r] + bi;
                if (mode == 0) {
                    Cf[(size_t)gr * N + gc] = v;
                } else {
                    int b = gr >> 11, s = gr & (Sc - 1);
                    int h = gc >> 6, d = gc & (Dc - 1);
                    Cb[(((size_t)b * Hc + h) * Sc + s) * Dc + d] = f2bf(v);
                }
            }
        }
    }
}

// ---------------------------------------------------------------------------
// Flash attention, bf16 MFMA (16x16x32). Same as round 2; epilogue now bf16.
// ---------------------------------------------------------------------------
__global__ __launch_bounds__(256) void attn_mfma_kernel(
    const unsigned short* __restrict__ Q, const unsigned short* __restrict__ K,
    const unsigned short* __restrict__ Vt, unsigned short* __restrict__ Y)
{
    __shared__ __align__(16) unsigned short Ks[64][72];    // [key][d]
    __shared__ __align__(16) unsigned short Vs[64][72];    // [d][key]
    __shared__ __align__(16) unsigned short Ps[4][16][40]; // per-wave [q][key]

    const int tid  = threadIdx.x;
    const int lane = tid & 63, wid = tid >> 6;
    const int g = lane >> 4, c16 = lane & 15;
    const int bh = blockIdx.x;
    const int q0 = blockIdx.y * 64;
    const size_t base = (size_t)bh * Sc * Dc;

    const unsigned short* Qp = Q + base + (size_t)(q0 + wid * 16 + c16) * Dc;
    short8 aq0 = *(const short8*)(Qp + g * 8);
    short8 aq1 = *(const short8*)(Qp + 32 + g * 8);

    f32x4 o[4] = {};
    float mrun[4], lsum[4];
#pragma unroll
    for (int r = 0; r < 4; ++r) { mrun[r] = -INFINITY; lsum[r] = 0.f; }

    const float scale = 0.125f;

    for (int kt = 0; kt < Sc / 64; ++kt) {
        __syncthreads();
        {
            int key = tid >> 2, db = (tid & 3) * 16;
            const unsigned short* ks = K + base + (size_t)(kt * 64 + key) * Dc + db;
            *(short8*)&Ks[key][db]     = *(const short8*)ks;
            *(short8*)&Ks[key][db + 8] = *(const short8*)(ks + 8);
            int d = tid >> 2, kb = (tid & 3) * 16;
            const unsigned short* vs = Vt + base + (size_t)d * Sc + kt * 64 + kb;
            *(short8*)&Vs[d][kb]     = *(const short8*)vs;
            *(short8*)&Vs[d][kb + 8] = *(const short8*)(vs + 8);
        }
        __syncthreads();

#pragma unroll
        for (int kc = 0; kc < 2; ++kc) {
            f32x4 z0 = {}, z1 = {};
            short8 b00 = *(const short8*)&Ks[kc * 32 + c16][g * 8];
            short8 b01 = *(const short8*)&Ks[kc * 32 + c16][32 + g * 8];
            f32x4 c0 = mfma16(aq0, b00, z0);
            c0 = mfma16(aq1, b01, c0);
            short8 b10 = *(const short8*)&Ks[kc * 32 + 16 + c16][g * 8];
            short8 b11 = *(const short8*)&Ks[kc * 32 + 16 + c16][32 + g * 8];
            f32x4 c1 = mfma16(aq0, b10, z1);
            c1 = mfma16(aq1, b11, c1);

            float corr[4];
#pragma unroll
            for (int r = 0; r < 4; ++r) {
                float s0 = c0[r] * scale, s1 = c1[r] * scale;
                float tm = fmaxf(s0, s1);
                tm = fmaxf(tm, __shfl_xor(tm, 1));
                tm = fmaxf(tm, __shfl_xor(tm, 2));
                tm = fmaxf(tm, __shfl_xor(tm, 4));
                tm = fmaxf(tm, __shfl_xor(tm, 8));
                float mnew = fmaxf(mrun[r], tm);
                corr[r] = __expf(mrun[r] - mnew);
                float p0 = __expf(s0 - mnew);
                float p1 = __expf(s1 - mnew);
                float ps = p0 + p1;
                ps += __shfl_xor(ps, 1);
                ps += __shfl_xor(ps, 2);
                ps += __shfl_xor(ps, 4);
                ps += __shfl_xor(ps, 8);
                lsum[r] = lsum[r] * corr[r] + ps;
                mrun[r] = mnew;
                Ps[wid][g * 4 + r][c16]      = f2bf(p0);
                Ps[wid][g * 4 + r][16 + c16] = f2bf(p1);
            }
#pragma unroll
            for (int dt = 0; dt < 4; ++dt) {
#pragma unroll
                for (int r = 0; r < 4; ++r) o[dt][r] *= corr[r];
            }
            asm volatile("s_waitcnt lgkmcnt(0)" ::: "memory");
            short8 ap = *(const short8*)&Ps[wid][c16][g * 8];
#pragma unroll
            for (int dt = 0; dt < 4; ++dt) {
                short8 bv = *(const short8*)&Vs[dt * 16 + c16][kc * 32 + g * 8];
                o[dt] = mfma16(ap, bv, o[dt]);
            }
        }
    }

    const int b = bh >> 4, h = bh & (Hc - 1);
#pragma unroll
    for (int r = 0; r < 4; ++r) {
        float inv = 1.f / lsum[r];
        int qg = q0 + wid * 16 + g * 4 + r;
        unsigned short* yrow = Y + ((size_t)b * Sc + qg) * Ec + h * Dc;
#pragma unroll
        for (int dt = 0; dt < 4; ++dt)
            yrow[dt * 16 + c16] = f2bf(o[dt][r] * inv);
    }
}

// ---------------------------------------------------------------------------
// LayerNorm, torch semantics: (x - mean)/(std + eps)*gain + beta, ddof=1.
// ---------------------------------------------------------------------------
__global__ __launch_bounds__(256) void ln_kernel(
    const float* __restrict__ Z, const float* __restrict__ gain,
    const float* __restrict__ beta, float* __restrict__ out)
{
    __shared__ float red0[4];
    __shared__ float red1[4];
    const int row = blockIdx.x;
    const int t = threadIdx.x;
    const float4* z4 = (const float4*)(Z + (size_t)row * Ec);
    float4 v = z4[t];

    float s = v.x + v.y + v.z + v.w;
#pragma unroll
    for (int off = 32; off > 0; off >>= 1) s += __shfl_down(s, off);
    if ((t & 63) == 0) red0[t >> 6] = s;
    __syncthreads();
    float mean = (red0[0] + red0[1] + red0[2] + red0[3]) * (1.0f / Ec);

    float dx = v.x - mean; float vs = dx * dx;
    dx = v.y - mean; vs += dx * dx;
    dx = v.z - mean; vs += dx * dx;
    dx = v.w - mean; vs += dx * dx;
#pragma unroll
    for (int off = 32; off > 0; off >>= 1) vs += __shfl_down(vs, off);
    if ((t & 63) == 0) red1[t >> 6] = vs;
    __syncthreads();
    float var = (red1[0] + red1[1] + red1[2] + red1[3]) * (1.0f / (Ec - 1));
    float inv = 1.0f / (sqrtf(var) + 1e-6f);

    float4 g = ((const float4*)gain)[t];
    float4 bb = ((const float4*)beta)[t];
    float4 o;
    o.x = (v.x - mean) * inv * g.x + bb.x;
    o.y = (v.y - mean) * inv * g.y + bb.y;
    o.z = (v.z - mean) * inv * g.z + bb.z;
    o.w = (v.w - mean) * inv * g.w + bb.w;
    ((float4*)(out + (size_t)row * Ec))[t] = o;
}

// ---------------------------------------------------------------------------
extern "C" void kernel_launch(void* const* d_in, const int* in_sizes, int n_in,
                              void* d_out, int out_size, void* d_ws, size_t ws_size,
                              hipStream_t stream)
{
    const float* x    = (const float*)d_in[0];
    const float* Wq   = (const float*)d_in[1];
    const float* bq   = (const float*)d_in[2];
    const float* Wk   = (const float*)d_in[3];
    const float* bk   = (const float*)d_in[4];
    const float* Wv   = (const float*)d_in[5];
    const float* bv   = (const float*)d_in[6];
    const float* Wp   = (const float*)d_in[7];
    const float* bp   = (const float*)d_in[8];
    const float* gain = (const float*)d_in[9];
    const float* beta = (const float*)d_in[10];

    const int M = Bc * Sc;                           // 4096
    const size_t MK  = (size_t)M * Ec;               // 4 M elems
    const size_t EE  = (size_t)Ec * Ec;              // 1 M elems

    unsigned short* xb  = (unsigned short*)d_ws;     // [0, 8MB)
    unsigned short* wqt = xb + MK;                   // [8,10)
    unsigned short* wkt = wqt + EE;                  // [10,12)
    unsigned short* wvt = wkt + EE;                  // [12,14)
    unsigned short* wpt = wvt + EE;                  // [14,16)
    unsigned short* qb  = wpt + EE;                  // [16,24)
    unsigned short* kb  = qb + MK;                   // [24,32)
    unsigned short* vb  = kb + MK;                   // [32,40)  (later reused as yb)
    unsigned short* vt  = vb + MK;                   // [40,48)
    unsigned short* yb  = vb;                        // reuse after transpose
    float* z = (float*)qb;                           // [16,32) fp32, after attn

    convert_x_kernel<<<(int)(MK / 8 / 256), 256, 0, stream>>>(x, xb, (int)(MK / 8));
    transpose_w_kernel<<<dim3(Ec / 64, Ec / 64, 4), 256, 0, stream>>>(
        Wq, Wk, Wv, Wp, wqt, wkt, wvt, wpt);

    dim3 gemm_grid(Ec / BN, M / BM);   // (16, 32)
    gemm_mfma_kernel<<<gemm_grid, 256, 0, stream>>>(xb, wqt, bq, nullptr, qb, M, Ec, Ec, 1);
    gemm_mfma_kernel<<<gemm_grid, 256, 0, stream>>>(xb, wkt, bk, nullptr, kb, M, Ec, Ec, 1);
    gemm_mfma_kernel<<<gemm_grid, 256, 0, stream>>>(xb, wvt, bv, nullptr, vb, M, Ec, Ec, 1);

    transpose_v_kernel<<<dim3(Bc * Hc, Sc / 64), 256, 0, stream>>>(vb, vt);

    dim3 attn_grid(Bc * Hc, Sc / 64);
    attn_mfma_kernel<<<attn_grid, 256, 0, stream>>>(qb, kb, vt, yb);

    gemm_mfma_kernel<<<gemm_grid, 256, 0, stream>>>(yb, wpt, bp, z, nullptr, M, Ec, Ec, 0);

    ln_kernel<<<M, 256, 0, stream>>>(z, gain, beta, (float*)d_out);
}

// Round 4
// 183.067 us; speedup vs baseline: 14.2197x; 1.3797x over previous
//
#include <hip/hip_runtime.h>
#include <hip/hip_bf16.h>
#include <math.h>

// Problem constants (fixed by setup_inputs)
constexpr int Bc = 2;
constexpr int Sc = 2048;
constexpr int Ec = 1024;
constexpr int Hc = 16;
constexpr int Dc = 64;

typedef __attribute__((ext_vector_type(8))) short short8;
typedef __attribute__((ext_vector_type(4))) short short4v;
typedef __attribute__((ext_vector_type(4))) float f32x4;

__device__ inline unsigned short f2bf(float x) {
    __hip_bfloat16 h = __float2bfloat16(x);
    return *reinterpret_cast<unsigned short*>(&h);
}

__device__ inline f32x4 mfma16(short8 a, short8 b, f32x4 c) {
    return __builtin_amdgcn_mfma_f32_16x16x32_bf16(a, b, c, 0, 0, 0);
}

// 16x16x16 bf16 (k=16): A/B = 4 bf16/lane (k = (lane>>4)*4 + j)
__device__ inline f32x4 mfma16k16(short4v a, short4v b, f32x4 c) {
#if __has_builtin(__builtin_amdgcn_mfma_f32_16x16x16bf16_1k)
    return __builtin_amdgcn_mfma_f32_16x16x16bf16_1k(a, b, c, 0, 0, 0);
#else
    f32x4 d;
    asm("v_mfma_f32_16x16x16_bf16 %0, %1, %2, %3"
        : "=v"(d) : "v"(a), "v"(b), "v"(c));
    return d;
#endif
}

__device__ inline void gload_lds16(const unsigned short* gsrc, unsigned short* ldst) {
    __builtin_amdgcn_global_load_lds(
        (const __attribute__((address_space(1))) unsigned int*)(const void*)gsrc,
        (__attribute__((address_space(3))) unsigned int*)(void*)ldst,
        16, 0, 0);
}

// ---------------------------------------------------------------------------
// x fp32 [M,K] -> bf16 [M,K]. 8 elems/thread.
// ---------------------------------------------------------------------------
__global__ __launch_bounds__(256) void convert_x_kernel(
    const float* __restrict__ X, unsigned short* __restrict__ Xb, int total8)
{
    int i = blockIdx.x * 256 + threadIdx.x;
    if (i >= total8) return;
    const float4* src = (const float4*)(X + (size_t)i * 8);
    float4 a = src[0], b = src[1];
    short8 o;
    o[0] = f2bf(a.x); o[1] = f2bf(a.y); o[2] = f2bf(a.z); o[3] = f2bf(a.w);
    o[4] = f2bf(b.x); o[5] = f2bf(b.y); o[6] = f2bf(b.z); o[7] = f2bf(b.w);
    *(short8*)(Xb + (size_t)i * 8) = o;
}

// ---------------------------------------------------------------------------
// W fp32 [K,N] -> Wt bf16 [N,K]; blockIdx.z selects which of 4 weights.
// ---------------------------------------------------------------------------
__global__ __launch_bounds__(256) void transpose_w_kernel(
    const float* __restrict__ W0, const float* __restrict__ W1,
    const float* __restrict__ W2, const float* __restrict__ W3,
    unsigned short* __restrict__ T0, unsigned short* __restrict__ T1,
    unsigned short* __restrict__ T2, unsigned short* __restrict__ T3)
{
    __shared__ unsigned short Ls[64][72];
    const float* W; unsigned short* T;
    switch (blockIdx.z) {
        case 0: W = W0; T = T0; break;
        case 1: W = W1; T = T1; break;
        case 2: W = W2; T = T2; break;
        default: W = W3; T = T3; break;
    }
    const int n0 = blockIdx.x * 64, k0 = blockIdx.y * 64;
    const int t = threadIdx.x;
    {
        int k = t >> 2, nb = (t & 3) * 16;
        const float* src = W + (size_t)(k0 + k) * Ec + n0 + nb;
#pragma unroll
        for (int j = 0; j < 16; ++j) Ls[k][nb + j] = f2bf(src[j]);
    }
    __syncthreads();
    {
        int n = t >> 2, kb = (t & 3) * 16;
        short8 o0, o1;
#pragma unroll
        for (int j = 0; j < 8; ++j) { o0[j] = Ls[kb + j][n]; o1[j] = Ls[kb + 8 + j][n]; }
        unsigned short* dst = T + (size_t)(n0 + n) * Ec + k0 + kb;
        *(short8*)dst = o0;
        *(short8*)(dst + 8) = o1;
    }
}

// ---------------------------------------------------------------------------
// V bf16 [B,H,S,D] -> Vt bf16 [B*H, D, S]. 64x64 LDS tile transpose.
// ---------------------------------------------------------------------------
__global__ __launch_bounds__(256) void transpose_v_kernel(
    const unsigned short* __restrict__ Vb, unsigned short* __restrict__ Vt)
{
    __shared__ unsigned short Ls[64][72];
    const int bh = blockIdx.x, st = blockIdx.y;
    const int t = threadIdx.x;
    {
        int s = t >> 2, db = (t & 3) * 16;
        const unsigned short* src = Vb + ((size_t)bh * Sc + st * 64 + s) * Dc + db;
        *(short8*)&Ls[s][db]     = *(const short8*)src;
        *(short8*)&Ls[s][db + 8] = *(const short8*)(src + 8);
    }
    __syncthreads();
    {
        int d = t >> 2, sb = (t & 3) * 16;
        short8 o0, o1;
#pragma unroll
        for (int j = 0; j < 8; ++j) { o0[j] = Ls[sb + j][d]; o1[j] = Ls[sb + 8 + j][d]; }
        unsigned short* dst = Vt + ((size_t)bh * Dc + d) * Sc + st * 64 + sb;
        *(short8*)dst = o0;
        *(short8*)(dst + 8) = o1;
    }
}

// ---------------------------------------------------------------------------
// bf16 MFMA GEMM: C = A[M,K]bf16 @ Bt[N,K]bf16^T + bias.  (unchanged)
// ---------------------------------------------------------------------------
constexpr int BM = 128, BN = 64, BK = 64;

__global__ __launch_bounds__(256) void gemm_mfma_kernel(
    const unsigned short* __restrict__ A, const unsigned short* __restrict__ Bt,
    const float* __restrict__ bias, float* __restrict__ Cf,
    unsigned short* __restrict__ Cb, int M, int N, int K, int mode)
{
    __shared__ unsigned short lds[2][BM * BK + BN * BK];   // 48 KB
    const int tid = threadIdx.x, lane = tid & 63, wid = tid >> 6;
    const int c16 = lane & 15, g = lane >> 4;
    const int wr = wid >> 1, wc = wid & 1;
    const int row0 = blockIdx.y * BM, col0 = blockIdx.x * BN;

    const int rsub = lane >> 3;
    const int colE = ((lane & 7) ^ rsub) * 8;

    f32x4 acc[4][2] = {};

    auto stage = [&](int buf, int k0) {
        unsigned short* Ab = &lds[buf][0];
        unsigned short* Bb = &lds[buf][BM * BK];
#pragma unroll
        for (int i = 0; i < 6; ++i) {
            int c = wid * 6 + i;
            if (c < 16) {
                const unsigned short* src = A + (size_t)(row0 + c * 8 + rsub) * K + k0 + colE;
                gload_lds16(src, Ab + c * 512);
            } else {
                int c2 = c - 16;
                const unsigned short* src = Bt + (size_t)(col0 + c2 * 8 + rsub) * K + k0 + colE;
                gload_lds16(src, Bb + c2 * 512);
            }
        }
    };

    stage(0, 0);
    __syncthreads();
    int cur = 0;
    const int NT = K / BK;
    for (int t = 0; t < NT; ++t) {
        if (t + 1 < NT) stage(cur ^ 1, (t + 1) * BK);
        const unsigned short* Ab = &lds[cur][0];
        const unsigned short* Bb = &lds[cur][BM * BK];
#pragma unroll
        for (int kk = 0; kk < 2; ++kk) {
            const int cb = ((kk * 64 + g * 16) ^ ((c16 & 7) << 4)) >> 1;
            short8 af[4], bfr[2];
#pragma unroll
            for (int m = 0; m < 4; ++m) {
                int row = wr * 64 + m * 16 + c16;
                af[m] = *(const short8*)(Ab + row * BK + cb);
            }
#pragma unroll
            for (int n = 0; n < 2; ++n) {
                int row = wc * 32 + n * 16 + c16;
                bfr[n] = *(const short8*)(Bb + row * BK + cb);
            }
#pragma unroll
            for (int m = 0; m < 4; ++m)
#pragma unroll
                for (int n = 0; n < 2; ++n)
                    acc[m][n] = mfma16(af[m], bfr[n], acc[m][n]);
        }
        __syncthreads();
        cur ^= 1;
    }

#pragma unroll
    for (int m = 0; m < 4; ++m) {
#pragma unroll
        for (int n = 0; n < 2; ++n) {
            int gc = col0 + wc * 32 + n * 16 + c16;
            float bi = bias[gc];
#pragma unroll
            for (int r = 0; r < 4; ++r) {
                int gr = row0 + wr * 64 + m * 16 + g * 4 + r;
                float v = acc[m][n][r] + bi;
                if (mode == 0) {
                    Cf[(size_t)gr * N + gc] = v;
                } else {
                    int b = gr >> 11, s = gr & (Sc - 1);
                    int h = gc >> 6, d = gc & (Dc - 1);
                    Cb[(((size_t)b * Hc + h) * Sc + s) * Dc + d] = f2bf(v);
                }
            }
        }
    }
}

// ---------------------------------------------------------------------------
// Flash attention v3: swapped QK^T, in-register softmax + P, swizzled LDS.
// grid (B*H, S/64); 256 threads = 4 waves; each wave owns 16 q-rows (= c16).
// LDS: double-buffered K,V tiles [64 rows][64 elems] linear rows, XOR-swizzled
// columns (byte ^= (row&7)<<4), staged via global_load_lds w=16 with
// pre-swizzled global source (both-sides rule).
//   QK^T: C[col=q=c16][row=key=g*4+r]  ->  lane q=c16 holds keys {4g+r}.
//   Softmax: per-lane scalars; cross-key reduce = 2 shfl_xor (16,32).
//   PV: P is already B-frag of mfma 16x16x16 (k=g*4+j) -> no LDS round-trip.
//   O: C[col=q=c16][row=d=dt*16+g*4+r].
// ---------------------------------------------------------------------------
__global__ __launch_bounds__(256) void attn_mfma_kernel(
    const unsigned short* __restrict__ Q, const unsigned short* __restrict__ K,
    const unsigned short* __restrict__ Vt, unsigned short* __restrict__ Y)
{
    __shared__ __align__(16) unsigned short lds[2][2][64 * 64];  // 32 KB

    const int tid  = threadIdx.x;
    const int lane = tid & 63, wid = tid >> 6;
    const int g = lane >> 4, c16 = lane & 15;
    const int bh = blockIdx.x;
    const int q0 = blockIdx.y * 64;
    const size_t base = (size_t)bh * Sc * Dc;

    // Q as B-frag: lane c16 = q, k elems = d
    const unsigned short* Qp = Q + base + (size_t)(q0 + wid * 16 + c16) * Dc;
    const short8 bq0 = *(const short8*)(Qp + g * 8);
    const short8 bq1 = *(const short8*)(Qp + 32 + g * 8);

    // staging source swizzle: lane L covers row rowblk*8 + (L>>3), slot L&7;
    // source col byte = 16*((L&7) ^ (L>>3))  (rows are 128B in global too)
    const int rsub = lane >> 3;
    const int srcoff = 16 * ((lane & 7) ^ rsub);

    f32x4 o[4] = {};
    float mrun = -INFINITY, lsum = 0.f;
    const float scale = 0.125f;   // 1/sqrt(64)

    auto stage = [&](int buf, int kt) {
        unsigned short* kb = &lds[buf][0][0];
        unsigned short* vb = &lds[buf][1][0];
#pragma unroll
        for (int c = 0; c < 2; ++c) {
            int rowblk = wid * 2 + c;            // 0..7, 8 rows each
            int row = rowblk * 8 + rsub;
            const unsigned short* ksrc = (const unsigned short*)
                ((const char*)(K + base + (size_t)(kt * 64 + row) * Dc) + srcoff);
            gload_lds16(ksrc, kb + rowblk * 512);
            const unsigned short* vsrc = (const unsigned short*)
                ((const char*)(Vt + base + (size_t)row * Sc + kt * 64) + srcoff);
            gload_lds16(vsrc, vb + rowblk * 512);
        }
    };

    stage(0, 0);
    __syncthreads();
    int cur = 0;

    for (int kt = 0; kt < Sc / 64; ++kt) {
        if (kt + 1 < Sc / 64) stage(cur ^ 1, kt + 1);
        const char* kb = (const char*)&lds[cur][0][0];
        const char* vb = (const char*)&lds[cur][1][0];

#pragma unroll
        for (int kc = 0; kc < 2; ++kc) {
            // K A-frags: rows = keys, swizzled read
            const int kr0 = kc * 32 + c16, kr1 = kr0 + 16;
            const int sw0 = (c16 & 7) << 4;     // (row&7)<<4, same for kr0/kr1
            short8 a0a = *(const short8*)(kb + kr0 * 128 + ((16 * g) ^ sw0));
            short8 a0b = *(const short8*)(kb + kr0 * 128 + ((64 + 16 * g) ^ sw0));
            short8 a1a = *(const short8*)(kb + kr1 * 128 + ((16 * g) ^ sw0));
            short8 a1b = *(const short8*)(kb + kr1 * 128 + ((64 + 16 * g) ^ sw0));
            f32x4 c0 = {}, c1 = {};
            c0 = mfma16(a0a, bq0, c0);
            c0 = mfma16(a0b, bq1, c0);
            c1 = mfma16(a1a, bq0, c1);
            c1 = mfma16(a1b, bq1, c1);

            // online softmax: lane owns row q=c16; keys 4g+r (c0), 16+4g+r (c1)
            float s0[4], s1[4];
            float tm = -INFINITY;
#pragma unroll
            for (int r = 0; r < 4; ++r) {
                s0[r] = c0[r] * scale; s1[r] = c1[r] * scale;
                tm = fmaxf(tm, fmaxf(s0[r], s1[r]));
            }
            tm = fmaxf(tm, __shfl_xor(tm, 16));
            tm = fmaxf(tm, __shfl_xor(tm, 32));
            float mnew = fmaxf(mrun, tm);
            float corr = __expf(mrun - mnew);
            float ps = 0.f;
            short4v pb0, pb1;
#pragma unroll
            for (int r = 0; r < 4; ++r) {
                float p0 = __expf(s0[r] - mnew);
                float p1 = __expf(s1[r] - mnew);
                ps += p0 + p1;
                pb0[r] = (short)f2bf(p0);
                pb1[r] = (short)f2bf(p1);
            }
            ps += __shfl_xor(ps, 16);
            ps += __shfl_xor(ps, 32);
            lsum = lsum * corr + ps;
            mrun = mnew;

#pragma unroll
            for (int dt = 0; dt < 4; ++dt)
#pragma unroll
                for (int r = 0; r < 4; ++r) o[dt][r] *= corr;

            // PV: A = V-tile (rows=d), B = P (in-register), k=16 each
#pragma unroll
            for (int dt = 0; dt < 4; ++dt) {
                const int drow = dt * 16 + c16;
                const int swv = (c16 & 7) << 4;
                short4v va0 = *(const short4v*)(vb + drow * 128 + ((kc * 64 + 8 * g) ^ swv));
                short4v va1 = *(const short4v*)(vb + drow * 128 + ((kc * 64 + 32 + 8 * g) ^ swv));
                o[dt] = mfma16k16(va0, pb0, o[dt]);
                o[dt] = mfma16k16(va1, pb1, o[dt]);
            }
        }
        __syncthreads();
        cur ^= 1;
    }

    // epilogue: lane holds O[q=c16][d=dt*16+g*4+r]
    const int b = bh >> 4, h = bh & (Hc - 1);
    const int qg = q0 + wid * 16 + c16;
    unsigned short* yrow = Y + ((size_t)b * Sc + qg) * Ec + h * Dc;
    const float inv = 1.f / lsum;
#pragma unroll
    for (int dt = 0; dt < 4; ++dt)
#pragma unroll
        for (int r = 0; r < 4; ++r)
            yrow[dt * 16 + g * 4 + r] = f2bf(o[dt][r] * inv);
}

// ---------------------------------------------------------------------------
// LayerNorm, torch semantics: (x - mean)/(std + eps)*gain + beta, ddof=1.
// ---------------------------------------------------------------------------
__global__ __launch_bounds__(256) void ln_kernel(
    const float* __restrict__ Z, const float* __restrict__ gain,
    const float* __restrict__ beta, float* __restrict__ out)
{
    __shared__ float red0[4];
    __shared__ float red1[4];
    const int row = blockIdx.x;
    const int t = threadIdx.x;
    const float4* z4 = (const float4*)(Z + (size_t)row * Ec);
    float4 v = z4[t];

    float s = v.x + v.y + v.z + v.w;
#pragma unroll
    for (int off = 32; off > 0; off >>= 1) s += __shfl_down(s, off);
    if ((t & 63) == 0) red0[t >> 6] = s;
    __syncthreads();
    float mean = (red0[0] + red0[1] + red0[2] + red0[3]) * (1.0f / Ec);

    float dx = v.x - mean; float vs = dx * dx;
    dx = v.y - mean; vs += dx * dx;
    dx = v.z - mean; vs += dx * dx;
    dx = v.w - mean; vs += dx * dx;
#pragma unroll
    for (int off = 32; off > 0; off >>= 1) vs += __shfl_down(vs, off);
    if ((t & 63) == 0) red1[t >> 6] = vs;
    __syncthreads();
    float var = (red1[0] + red1[1] + red1[2] + red1[3]) * (1.0f / (Ec - 1));
    float inv = 1.0f / (sqrtf(var) + 1e-6f);

    float4 g = ((const float4*)gain)[t];
    float4 bb = ((const float4*)beta)[t];
    float4 o;
    o.x = (v.x - mean) * inv * g.x + bb.x;
    o.y = (v.y - mean) * inv * g.y + bb.y;
    o.z = (v.z - mean) * inv * g.z + bb.z;
    o.w = (v.w - mean) * inv * g.w + bb.w;
    ((float4*)(out + (size_t)row * Ec))[t] = o;
}

// ---------------------------------------------------------------------------
extern "C" void kernel_launch(void* const* d_in, const int* in_sizes, int n_in,
                              void* d_out, int out_size, void* d_ws, size_t ws_size,
                              hipStream_t stream)
{
    const float* x    = (const float*)d_in[0];
    const float* Wq   = (const float*)d_in[1];
    const float* bq   = (const float*)d_in[2];
    const float* Wk   = (const float*)d_in[3];
    const float* bk   = (const float*)d_in[4];
    const float* Wv   = (const float*)d_in[5];
    const float* bv   = (const float*)d_in[6];
    const float* Wp   = (const float*)d_in[7];
    const float* bp   = (const float*)d_in[8];
    const float* gain = (const float*)d_in[9];
    const float* beta = (const float*)d_in[10];

    const int M = Bc * Sc;                           // 4096
    const size_t MK  = (size_t)M * Ec;               // 4 M elems
    const size_t EE  = (size_t)Ec * Ec;              // 1 M elems

    unsigned short* xb  = (unsigned short*)d_ws;     // [0, 8MB)
    unsigned short* wqt = xb + MK;                   // [8,10)
    unsigned short* wkt = wqt + EE;                  // [10,12)
    unsigned short* wvt = wkt + EE;                  // [12,14)
    unsigned short* wpt = wvt + EE;                  // [14,16)
    unsigned short* qb  = wpt + EE;                  // [16,24)
    unsigned short* kb  = qb + MK;                   // [24,32)
    unsigned short* vb  = kb + MK;                   // [32,40)
    unsigned short* vt  = vb + MK;                   // [40,48)
    unsigned short* yb  = vb;                        // reuse after transpose
    float* z = (float*)qb;                           // fp32, after attn

    convert_x_kernel<<<(int)(MK / 8 / 256), 256, 0, stream>>>(x, xb, (int)(MK / 8));
    transpose_w_kernel<<<dim3(Ec / 64, Ec / 64, 4), 256, 0, stream>>>(
        Wq, Wk, Wv, Wp, wqt, wkt, wvt, wpt);

    dim3 gemm_grid(Ec / BN, M / BM);   // (16, 32)
    gemm_mfma_kernel<<<gemm_grid, 256, 0, stream>>>(xb, wqt, bq, nullptr, qb, M, Ec, Ec, 1);
    gemm_mfma_kernel<<<gemm_grid, 256, 0, stream>>>(xb, wkt, bk, nullptr, kb, M, Ec, Ec, 1);
    gemm_mfma_kernel<<<gemm_grid, 256, 0, stream>>>(xb, wvt, bv, nullptr, vb, M, Ec, Ec, 1);

    transpose_v_kernel<<<dim3(Bc * Hc, Sc / 64), 256, 0, stream>>>(vb, vt);

    dim3 attn_grid(Bc * Hc, Sc / 64);
    attn_mfma_kernel<<<attn_grid, 256, 0, stream>>>(qb, kb, vt, yb);

    gemm_mfma_kernel<<<gemm_grid, 256, 0, stream>>>(yb, wpt, bp, z, nullptr, M, Ec, Ec, 0);

    ln_kernel<<<M, 256, 0, stream>>>(z, gain, beta, (float*)d_out);
}

// Round 5
// 177.681 us; speedup vs baseline: 14.6507x; 1.0303x over previous
//
#include <hip/hip_runtime.h>
#include <hip/hip_bf16.h>
#include <math.h>

// Problem constants (fixed by setup_inputs)
constexpr int Bc = 2;
constexpr int Sc = 2048;
constexpr int Ec = 1024;
constexpr int Hc = 16;
constexpr int Dc = 64;

typedef __attribute__((ext_vector_type(8))) short short8;
typedef __attribute__((ext_vector_type(4))) short short4v;
typedef __attribute__((ext_vector_type(4))) float f32x4;

__device__ inline unsigned short f2bf(float x) {
    __hip_bfloat16 h = __float2bfloat16(x);
    return *reinterpret_cast<unsigned short*>(&h);
}

__device__ inline f32x4 mfma16(short8 a, short8 b, f32x4 c) {
    return __builtin_amdgcn_mfma_f32_16x16x32_bf16(a, b, c, 0, 0, 0);
}

// 16x16x16 bf16 (k=16): A/B = 4 bf16/lane (k = (lane>>4)*4 + j)
__device__ inline f32x4 mfma16k16(short4v a, short4v b, f32x4 c) {
#if __has_builtin(__builtin_amdgcn_mfma_f32_16x16x16bf16_1k)
    return __builtin_amdgcn_mfma_f32_16x16x16bf16_1k(a, b, c, 0, 0, 0);
#else
    f32x4 d;
    asm("v_mfma_f32_16x16x16_bf16 %0, %1, %2, %3"
        : "=v"(d) : "v"(a), "v"(b), "v"(c));
    return d;
#endif
}

__device__ inline void gload_lds16(const unsigned short* gsrc, unsigned short* ldst) {
    __builtin_amdgcn_global_load_lds(
        (const __attribute__((address_space(1))) unsigned int*)(const void*)gsrc,
        (__attribute__((address_space(3))) unsigned int*)(void*)ldst,
        16, 0, 0);
}

// ---------------------------------------------------------------------------
// x fp32 [M,K] -> bf16 [M,K]. 8 elems/thread.
// ---------------------------------------------------------------------------
__global__ __launch_bounds__(256) void convert_x_kernel(
    const float* __restrict__ X, unsigned short* __restrict__ Xb, int total8)
{
    int i = blockIdx.x * 256 + threadIdx.x;
    if (i >= total8) return;
    const float4* src = (const float4*)(X + (size_t)i * 8);
    float4 a = src[0], b = src[1];
    short8 o;
    o[0] = f2bf(a.x); o[1] = f2bf(a.y); o[2] = f2bf(a.z); o[3] = f2bf(a.w);
    o[4] = f2bf(b.x); o[5] = f2bf(b.y); o[6] = f2bf(b.z); o[7] = f2bf(b.w);
    *(short8*)(Xb + (size_t)i * 8) = o;
}

// ---------------------------------------------------------------------------
// W fp32 [K,N] -> Wt bf16 [N,K]; blockIdx.z selects which of 4 weights.
// ---------------------------------------------------------------------------
__global__ __launch_bounds__(256) void transpose_w_kernel(
    const float* __restrict__ W0, const float* __restrict__ W1,
    const float* __restrict__ W2, const float* __restrict__ W3,
    unsigned short* __restrict__ T0, unsigned short* __restrict__ T1,
    unsigned short* __restrict__ T2, unsigned short* __restrict__ T3)
{
    __shared__ unsigned short Ls[64][72];
    const float* W; unsigned short* T;
    switch (blockIdx.z) {
        case 0: W = W0; T = T0; break;
        case 1: W = W1; T = T1; break;
        case 2: W = W2; T = T2; break;
        default: W = W3; T = T3; break;
    }
    const int n0 = blockIdx.x * 64, k0 = blockIdx.y * 64;
    const int t = threadIdx.x;
    {
        int k = t >> 2, nb = (t & 3) * 16;
        const float* src = W + (size_t)(k0 + k) * Ec + n0 + nb;
#pragma unroll
        for (int j = 0; j < 16; ++j) Ls[k][nb + j] = f2bf(src[j]);
    }
    __syncthreads();
    {
        int n = t >> 2, kb = (t & 3) * 16;
        short8 o0, o1;
#pragma unroll
        for (int j = 0; j < 8; ++j) { o0[j] = Ls[kb + j][n]; o1[j] = Ls[kb + 8 + j][n]; }
        unsigned short* dst = T + (size_t)(n0 + n) * Ec + k0 + kb;
        *(short8*)dst = o0;
        *(short8*)(dst + 8) = o1;
    }
}

// ---------------------------------------------------------------------------
// V bf16 [B,H,S,D] -> Vt bf16 [B*H, D, S]. 64x64 LDS tile transpose.
// ---------------------------------------------------------------------------
__global__ __launch_bounds__(256) void transpose_v_kernel(
    const unsigned short* __restrict__ Vb, unsigned short* __restrict__ Vt)
{
    __shared__ unsigned short Ls[64][72];
    const int bh = blockIdx.x, st = blockIdx.y;
    const int t = threadIdx.x;
    {
        int s = t >> 2, db = (t & 3) * 16;
        const unsigned short* src = Vb + ((size_t)bh * Sc + st * 64 + s) * Dc + db;
        *(short8*)&Ls[s][db]     = *(const short8*)src;
        *(short8*)&Ls[s][db + 8] = *(const short8*)(src + 8);
    }
    __syncthreads();
    {
        int d = t >> 2, sb = (t & 3) * 16;
        short8 o0, o1;
#pragma unroll
        for (int j = 0; j < 8; ++j) { o0[j] = Ls[sb + j][d]; o1[j] = Ls[sb + 8 + j][d]; }
        unsigned short* dst = Vt + ((size_t)bh * Dc + d) * Sc + st * 64 + sb;
        *(short8*)dst = o0;
        *(short8*)(dst + 8) = o1;
    }
}

// ---------------------------------------------------------------------------
// bf16 MFMA GEMM: C = A[M,K]bf16 @ Bt[N,K]bf16^T + bias.  (unchanged)
// ---------------------------------------------------------------------------
constexpr int BM = 128, BN = 64, BK = 64;

__global__ __launch_bounds__(256) void gemm_mfma_kernel(
    const unsigned short* __restrict__ A, const unsigned short* __restrict__ Bt,
    const float* __restrict__ bias, float* __restrict__ Cf,
    unsigned short* __restrict__ Cb, int M, int N, int K, int mode)
{
    __shared__ unsigned short lds[2][BM * BK + BN * BK];   // 48 KB
    const int tid = threadIdx.x, lane = tid & 63, wid = tid >> 6;
    const int c16 = lane & 15, g = lane >> 4;
    const int wr = wid >> 1, wc = wid & 1;
    const int row0 = blockIdx.y * BM, col0 = blockIdx.x * BN;

    const int rsub = lane >> 3;
    const int colE = ((lane & 7) ^ rsub) * 8;

    f32x4 acc[4][2] = {};

    auto stage = [&](int buf, int k0) {
        unsigned short* Ab = &lds[buf][0];
        unsigned short* Bb = &lds[buf][BM * BK];
#pragma unroll
        for (int i = 0; i < 6; ++i) {
            int c = wid * 6 + i;
            if (c < 16) {
                const unsigned short* src = A + (size_t)(row0 + c * 8 + rsub) * K + k0 + colE;
                gload_lds16(src, Ab + c * 512);
            } else {
                int c2 = c - 16;
                const unsigned short* src = Bt + (size_t)(col0 + c2 * 8 + rsub) * K + k0 + colE;
                gload_lds16(src, Bb + c2 * 512);
            }
        }
    };

    stage(0, 0);
    __syncthreads();
    int cur = 0;
    const int NT = K / BK;
    for (int t = 0; t < NT; ++t) {
        if (t + 1 < NT) stage(cur ^ 1, (t + 1) * BK);
        const unsigned short* Ab = &lds[cur][0];
        const unsigned short* Bb = &lds[cur][BM * BK];
#pragma unroll
        for (int kk = 0; kk < 2; ++kk) {
            const int cb = ((kk * 64 + g * 16) ^ ((c16 & 7) << 4)) >> 1;
            short8 af[4], bfr[2];
#pragma unroll
            for (int m = 0; m < 4; ++m) {
                int row = wr * 64 + m * 16 + c16;
                af[m] = *(const short8*)(Ab + row * BK + cb);
            }
#pragma unroll
            for (int n = 0; n < 2; ++n) {
                int row = wc * 32 + n * 16 + c16;
                bfr[n] = *(const short8*)(Bb + row * BK + cb);
            }
#pragma unroll
            for (int m = 0; m < 4; ++m)
#pragma unroll
                for (int n = 0; n < 2; ++n)
                    acc[m][n] = mfma16(af[m], bfr[n], acc[m][n]);
        }
        __syncthreads();
        cur ^= 1;
    }

#pragma unroll
    for (int m = 0; m < 4; ++m) {
#pragma unroll
        for (int n = 0; n < 2; ++n) {
            int gc = col0 + wc * 32 + n * 16 + c16;
            float bi = bias[gc];
#pragma unroll
            for (int r = 0; r < 4; ++r) {
                int gr = row0 + wr * 64 + m * 16 + g * 4 + r;
                float v = acc[m][n][r] + bi;
                if (mode == 0) {
                    Cf[(size_t)gr * N + gc] = v;
                } else {
                    int b = gr >> 11, s = gr & (Sc - 1);
                    int h = gc >> 6, d = gc & (Dc - 1);
                    Cb[(((size_t)b * Hc + h) * Sc + s) * Dc + d] = f2bf(v);
                }
            }
        }
    }
}

// ---------------------------------------------------------------------------
// Flash attention v4: swapped QK^T, single softmax pass per 64-key tile,
// defer-max (T13, THR=8 in base-2 domain), exp2 domain, setprio (T5).
// grid (B*H, S/64); 256 threads = 4 waves; each wave owns 16 q-rows (= c16).
// LDS: double-buffered K,V tiles [64 rows][64 elems], XOR-swizzled columns
// (byte ^= (row&7)<<4) staged via global_load_lds w=16, pre-swizzled source.
//   QK^T: C[col=q=c16][row=key=ct*16+g*4+r] -> lane q=c16 holds 16 key-scores.
//   Softmax: per-lane scalars; cross-key reduce = 2 shfl_xor (16,32) per tile.
//   PV: P is already the B-frag of mfma 16x16x16 (k=g*4+j) -> no LDS trip.
// ---------------------------------------------------------------------------
__global__ __launch_bounds__(256) void attn_mfma_kernel(
    const unsigned short* __restrict__ Q, const unsigned short* __restrict__ K,
    const unsigned short* __restrict__ Vt, unsigned short* __restrict__ Y)
{
    __shared__ __align__(16) unsigned short lds[2][2][64 * 64];  // 32 KB

    const int tid  = threadIdx.x;
    const int lane = tid & 63, wid = tid >> 6;
    const int g = lane >> 4, c16 = lane & 15;
    const int bh = blockIdx.x;
    const int q0 = blockIdx.y * 64;
    const size_t base = (size_t)bh * Sc * Dc;

    // Q as B-frag: lane c16 = q, k elems = d
    const unsigned short* Qp = Q + base + (size_t)(q0 + wid * 16 + c16) * Dc;
    const short8 bq0 = *(const short8*)(Qp + g * 8);
    const short8 bq1 = *(const short8*)(Qp + 32 + g * 8);

    const int rsub = lane >> 3;
    const int srcoff = 16 * ((lane & 7) ^ rsub);

    f32x4 o[4] = {};
    float mrun = -INFINITY, lsum = 0.f;
    const float sl2e = 0.125f * 1.44269504f;   // scale * log2(e)

    auto stage = [&](int buf, int kt) {
        unsigned short* kb = &lds[buf][0][0];
        unsigned short* vb = &lds[buf][1][0];
#pragma unroll
        for (int c = 0; c < 2; ++c) {
            int rowblk = wid * 2 + c;
            int row = rowblk * 8 + rsub;
            const unsigned short* ksrc = (const unsigned short*)
                ((const char*)(K + base + (size_t)(kt * 64 + row) * Dc) + srcoff);
            gload_lds16(ksrc, kb + rowblk * 512);
            const unsigned short* vsrc = (const unsigned short*)
                ((const char*)(Vt + base + (size_t)row * Sc + kt * 64) + srcoff);
            gload_lds16(vsrc, vb + rowblk * 512);
        }
    };

    stage(0, 0);
    __syncthreads();
    int cur = 0;

    for (int kt = 0; kt < Sc / 64; ++kt) {
        if (kt + 1 < Sc / 64) stage(cur ^ 1, kt + 1);
        const char* kb = (const char*)&lds[cur][0][0];
        const char* vb = (const char*)&lds[cur][1][0];
        const int sw = (c16 & 7) << 4;

        // QK^T: 4 column tiles of 16 keys, K-dim 64 = 2 MFMAs each
        f32x4 c[4];
        __builtin_amdgcn_s_setprio(1);
#pragma unroll
        for (int ct = 0; ct < 4; ++ct) {
            const int kr = ct * 16 + c16;
            short8 alo = *(const short8*)(kb + kr * 128 + ((16 * g) ^ sw));
            short8 ahi = *(const short8*)(kb + kr * 128 + ((64 + 16 * g) ^ sw));
            f32x4 z = {};
            z = mfma16(alo, bq0, z);
            c[ct] = mfma16(ahi, bq1, z);
        }
        __builtin_amdgcn_s_setprio(0);

        // ---- single softmax update over 64 keys (base-2 domain) ----
        float s[4][4];
        float tm = -INFINITY;
#pragma unroll
        for (int ct = 0; ct < 4; ++ct)
#pragma unroll
            for (int r = 0; r < 4; ++r) {
                s[ct][r] = c[ct][r] * sl2e;
                tm = fmaxf(tm, s[ct][r]);
            }
        tm = fmaxf(tm, __shfl_xor(tm, 16));
        tm = fmaxf(tm, __shfl_xor(tm, 32));
        // defer-max: only rescale when max grew by > 8 (p bounded by 2^8)
        if (!__all(tm <= mrun + 8.0f)) {
            float mnew = fmaxf(mrun, tm);
            float corr = exp2f(mrun - mnew);
            lsum *= corr;
#pragma unroll
            for (int dt = 0; dt < 4; ++dt)
#pragma unroll
                for (int r = 0; r < 4; ++r) o[dt][r] *= corr;
            mrun = mnew;
        }
        float ps = 0.f;
        short4v pb[4];
#pragma unroll
        for (int ct = 0; ct < 4; ++ct)
#pragma unroll
            for (int r = 0; r < 4; ++r) {
                float p = exp2f(s[ct][r] - mrun);
                ps += p;
                pb[ct][r] = (short)f2bf(p);
            }
        ps += __shfl_xor(ps, 16);
        ps += __shfl_xor(ps, 32);
        lsum += ps;

        // PV: A = V-tile (rows=d), B = P (in-register), k=16 per ct
        __builtin_amdgcn_s_setprio(1);
#pragma unroll
        for (int dt = 0; dt < 4; ++dt) {
            const int drow = dt * 16 + c16;
#pragma unroll
            for (int ct = 0; ct < 4; ++ct) {
                short4v va = *(const short4v*)(vb + drow * 128 + ((ct * 32 + 8 * g) ^ sw));
                o[dt] = mfma16k16(va, pb[ct], o[dt]);
            }
        }
        __builtin_amdgcn_s_setprio(0);
        __syncthreads();
        cur ^= 1;
    }

    // epilogue: lane holds O[q=c16][d=dt*16+g*4+r]
    const int b = bh >> 4, h = bh & (Hc - 1);
    const int qg = q0 + wid * 16 + c16;
    unsigned short* yrow = Y + ((size_t)b * Sc + qg) * Ec + h * Dc;
    const float inv = 1.f / lsum;
#pragma unroll
    for (int dt = 0; dt < 4; ++dt)
#pragma unroll
        for (int r = 0; r < 4; ++r)
            yrow[dt * 16 + g * 4 + r] = f2bf(o[dt][r] * inv);
}

// ---------------------------------------------------------------------------
// LayerNorm, torch semantics: (x - mean)/(std + eps)*gain + beta, ddof=1.
// ---------------------------------------------------------------------------
__global__ __launch_bounds__(256) void ln_kernel(
    const float* __restrict__ Z, const float* __restrict__ gain,
    const float* __restrict__ beta, float* __restrict__ out)
{
    __shared__ float red0[4];
    __shared__ float red1[4];
    const int row = blockIdx.x;
    const int t = threadIdx.x;
    const float4* z4 = (const float4*)(Z + (size_t)row * Ec);
    float4 v = z4[t];

    float s = v.x + v.y + v.z + v.w;
#pragma unroll
    for (int off = 32; off > 0; off >>= 1) s += __shfl_down(s, off);
    if ((t & 63) == 0) red0[t >> 6] = s;
    __syncthreads();
    float mean = (red0[0] + red0[1] + red0[2] + red0[3]) * (1.0f / Ec);

    float dx = v.x - mean; float vs = dx * dx;
    dx = v.y - mean; vs += dx * dx;
    dx = v.z - mean; vs += dx * dx;
    dx = v.w - mean; vs += dx * dx;
#pragma unroll
    for (int off = 32; off > 0; off >>= 1) vs += __shfl_down(vs, off);
    if ((t & 63) == 0) red1[t >> 6] = vs;
    __syncthreads();
    float var = (red1[0] + red1[1] + red1[2] + red1[3]) * (1.0f / (Ec - 1));
    float inv = 1.0f / (sqrtf(var) + 1e-6f);

    float4 g = ((const float4*)gain)[t];
    float4 bb = ((const float4*)beta)[t];
    float4 o;
    o.x = (v.x - mean) * inv * g.x + bb.x;
    o.y = (v.y - mean) * inv * g.y + bb.y;
    o.z = (v.z - mean) * inv * g.z + bb.z;
    o.w = (v.w - mean) * inv * g.w + bb.w;
    ((float4*)(out + (size_t)row * Ec))[t] = o;
}

// ---------------------------------------------------------------------------
extern "C" void kernel_launch(void* const* d_in, const int* in_sizes, int n_in,
                              void* d_out, int out_size, void* d_ws, size_t ws_size,
                              hipStream_t stream)
{
    const float* x    = (const float*)d_in[0];
    const float* Wq   = (const float*)d_in[1];
    const float* bq   = (const float*)d_in[2];
    const float* Wk   = (const float*)d_in[3];
    const float* bk   = (const float*)d_in[4];
    const float* Wv   = (const float*)d_in[5];
    const float* bv   = (const float*)d_in[6];
    const float* Wp   = (const float*)d_in[7];
    const float* bp   = (const float*)d_in[8];
    const float* gain = (const float*)d_in[9];
    const float* beta = (const float*)d_in[10];

    const int M = Bc * Sc;                           // 4096
    const size_t MK  = (size_t)M * Ec;               // 4 M elems
    const size_t EE  = (size_t)Ec * Ec;              // 1 M elems

    unsigned short* xb  = (unsigned short*)d_ws;     // [0, 8MB)
    unsigned short* wqt = xb + MK;                   // [8,10)
    unsigned short* wkt = wqt + EE;                  // [10,12)
    unsigned short* wvt = wkt + EE;                  // [12,14)
    unsigned short* wpt = wvt + EE;                  // [14,16)
    unsigned short* qb  = wpt + EE;                  // [16,24)
    unsigned short* kb  = qb + MK;                   // [24,32)
    unsigned short* vb  = kb + MK;                   // [32,40)
    unsigned short* vt  = vb + MK;                   // [40,48)
    unsigned short* yb  = vb;                        // reuse after transpose
    float* z = (float*)qb;                           // fp32, after attn

    convert_x_kernel<<<(int)(MK / 8 / 256), 256, 0, stream>>>(x, xb, (int)(MK / 8));
    transpose_w_kernel<<<dim3(Ec / 64, Ec / 64, 4), 256, 0, stream>>>(
        Wq, Wk, Wv, Wp, wqt, wkt, wvt, wpt);

    dim3 gemm_grid(Ec / BN, M / BM);   // (16, 32)
    gemm_mfma_kernel<<<gemm_grid, 256, 0, stream>>>(xb, wqt, bq, nullptr, qb, M, Ec, Ec, 1);
    gemm_mfma_kernel<<<gemm_grid, 256, 0, stream>>>(xb, wkt, bk, nullptr, kb, M, Ec, Ec, 1);
    gemm_mfma_kernel<<<gemm_grid, 256, 0, stream>>>(xb, wvt, bv, nullptr, vb, M, Ec, Ec, 1);

    transpose_v_kernel<<<dim3(Bc * Hc, Sc / 64), 256, 0, stream>>>(vb, vt);

    dim3 attn_grid(Bc * Hc, Sc / 64);
    attn_mfma_kernel<<<attn_grid, 256, 0, stream>>>(qb, kb, vt, yb);

    gemm_mfma_kernel<<<gemm_grid, 256, 0, stream>>>(yb, wpt, bp, z, nullptr, M, Ec, Ec, 0);

    ln_kernel<<<M, 256, 0, stream>>>(z, gain, beta, (float*)d_out);
}

// Round 6
// 162.876 us; speedup vs baseline: 15.9825x; 1.0909x over previous
//
#include <hip/hip_runtime.h>
#include <hip/hip_bf16.h>
#include <math.h>

// Problem constants (fixed by setup_inputs)
constexpr int Bc = 2;
constexpr int Sc = 2048;
constexpr int Ec = 1024;
constexpr int Hc = 16;
constexpr int Dc = 64;

typedef __attribute__((ext_vector_type(8))) short short8;
typedef __attribute__((ext_vector_type(4))) short short4v;
typedef __attribute__((ext_vector_type(2))) int int2v;
typedef __attribute__((ext_vector_type(4))) float f32x4;

__device__ inline unsigned short f2bf(float x) {
    __hip_bfloat16 h = __float2bfloat16(x);
    return *reinterpret_cast<unsigned short*>(&h);
}

__device__ inline f32x4 mfma16(short8 a, short8 b, f32x4 c) {
    return __builtin_amdgcn_mfma_f32_16x16x32_bf16(a, b, c, 0, 0, 0);
}

// 16x16x16 bf16 (k=16): A/B = 4 bf16/lane (k = (lane>>4)*4 + j)
__device__ inline f32x4 mfma16k16(short4v a, short4v b, f32x4 c) {
#if __has_builtin(__builtin_amdgcn_mfma_f32_16x16x16bf16_1k)
    return __builtin_amdgcn_mfma_f32_16x16x16bf16_1k(a, b, c, 0, 0, 0);
#else
    f32x4 d;
    asm("v_mfma_f32_16x16x16_bf16 %0, %1, %2, %3"
        : "=v"(d) : "v"(a), "v"(b), "v"(c));
    return d;
#endif
}

// single-instruction 2^x (pure, schedulable)
__device__ inline float exp2_fast(float x) {
    float r;
    asm("v_exp_f32 %0, %1" : "=v"(r) : "v"(x));
    return r;
}

// pack 2 fp32 -> 2 bf16 in one dword (RNE), one instruction
__device__ inline int cvt_pk_bf16(float lo, float hi) {
    int r;
    asm("v_cvt_pk_bf16_f32 %0, %1, %2" : "=v"(r) : "v"(lo), "v"(hi));
    return r;
}

__device__ inline void gload_lds16(const unsigned short* gsrc, unsigned short* ldst) {
    __builtin_amdgcn_global_load_lds(
        (const __attribute__((address_space(1))) unsigned int*)(const void*)gsrc,
        (__attribute__((address_space(3))) unsigned int*)(void*)ldst,
        16, 0, 0);
}

// ---------------------------------------------------------------------------
// x fp32 [M,K] -> bf16 [M,K]. 8 elems/thread.
// ---------------------------------------------------------------------------
__global__ __launch_bounds__(256) void convert_x_kernel(
    const float* __restrict__ X, unsigned short* __restrict__ Xb, int total8)
{
    int i = blockIdx.x * 256 + threadIdx.x;
    if (i >= total8) return;
    const float4* src = (const float4*)(X + (size_t)i * 8);
    float4 a = src[0], b = src[1];
    short8 o;
    o[0] = f2bf(a.x); o[1] = f2bf(a.y); o[2] = f2bf(a.z); o[3] = f2bf(a.w);
    o[4] = f2bf(b.x); o[5] = f2bf(b.y); o[6] = f2bf(b.z); o[7] = f2bf(b.w);
    *(short8*)(Xb + (size_t)i * 8) = o;
}

// ---------------------------------------------------------------------------
// W fp32 [K,N] -> Wt bf16 [N,K]; blockIdx.z selects which of 4 weights.
// ---------------------------------------------------------------------------
__global__ __launch_bounds__(256) void transpose_w_kernel(
    const float* __restrict__ W0, const float* __restrict__ W1,
    const float* __restrict__ W2, const float* __restrict__ W3,
    unsigned short* __restrict__ T0, unsigned short* __restrict__ T1,
    unsigned short* __restrict__ T2, unsigned short* __restrict__ T3)
{
    __shared__ unsigned short Ls[64][72];
    const float* W; unsigned short* T;
    switch (blockIdx.z) {
        case 0: W = W0; T = T0; break;
        case 1: W = W1; T = T1; break;
        case 2: W = W2; T = T2; break;
        default: W = W3; T = T3; break;
    }
    const int n0 = blockIdx.x * 64, k0 = blockIdx.y * 64;
    const int t = threadIdx.x;
    {
        int k = t >> 2, nb = (t & 3) * 16;
        const float* src = W + (size_t)(k0 + k) * Ec + n0 + nb;
#pragma unroll
        for (int j = 0; j < 16; ++j) Ls[k][nb + j] = f2bf(src[j]);
    }
    __syncthreads();
    {
        int n = t >> 2, kb = (t & 3) * 16;
        short8 o0, o1;
#pragma unroll
        for (int j = 0; j < 8; ++j) { o0[j] = Ls[kb + j][n]; o1[j] = Ls[kb + 8 + j][n]; }
        unsigned short* dst = T + (size_t)(n0 + n) * Ec + k0 + kb;
        *(short8*)dst = o0;
        *(short8*)(dst + 8) = o1;
    }
}

// ---------------------------------------------------------------------------
// V bf16 [B,H,S,D] -> Vt bf16 [B*H, D, S]. 64x64 LDS tile transpose.
// ---------------------------------------------------------------------------
__global__ __launch_bounds__(256) void transpose_v_kernel(
    const unsigned short* __restrict__ Vb, unsigned short* __restrict__ Vt)
{
    __shared__ unsigned short Ls[64][72];
    const int bh = blockIdx.x, st = blockIdx.y;
    const int t = threadIdx.x;
    {
        int s = t >> 2, db = (t & 3) * 16;
        const unsigned short* src = Vb + ((size_t)bh * Sc + st * 64 + s) * Dc + db;
        *(short8*)&Ls[s][db]     = *(const short8*)src;
        *(short8*)&Ls[s][db + 8] = *(const short8*)(src + 8);
    }
    __syncthreads();
    {
        int d = t >> 2, sb = (t & 3) * 16;
        short8 o0, o1;
#pragma unroll
        for (int j = 0; j < 8; ++j) { o0[j] = Ls[sb + j][d]; o1[j] = Ls[sb + 8 + j][d]; }
        unsigned short* dst = Vt + ((size_t)bh * Dc + d) * Sc + st * 64 + sb;
        *(short8*)dst = o0;
        *(short8*)(dst + 8) = o1;
    }
}

// ---------------------------------------------------------------------------
// bf16 MFMA GEMM: C = (A[M,K]bf16 @ Bt[N,K]bf16^T + bias) * oscale.
// mode 0: fp32 [M,N].  mode 1: bf16 [B,H,S,D] head scatter.
// ---------------------------------------------------------------------------
constexpr int BM = 128, BN = 64, BK = 64;

__global__ __launch_bounds__(256) void gemm_mfma_kernel(
    const unsigned short* __restrict__ A, const unsigned short* __restrict__ Bt,
    const float* __restrict__ bias, float* __restrict__ Cf,
    unsigned short* __restrict__ Cb, int M, int N, int K, int mode, float oscale)
{
    __shared__ unsigned short lds[2][BM * BK + BN * BK];   // 48 KB
    const int tid = threadIdx.x, lane = tid & 63, wid = tid >> 6;
    const int c16 = lane & 15, g = lane >> 4;
    const int wr = wid >> 1, wc = wid & 1;
    const int row0 = blockIdx.y * BM, col0 = blockIdx.x * BN;

    const int rsub = lane >> 3;
    const int colE = ((lane & 7) ^ rsub) * 8;

    f32x4 acc[4][2] = {};

    auto stage = [&](int buf, int k0) {
        unsigned short* Ab = &lds[buf][0];
        unsigned short* Bb = &lds[buf][BM * BK];
#pragma unroll
        for (int i = 0; i < 6; ++i) {
            int c = wid * 6 + i;
            if (c < 16) {
                const unsigned short* src = A + (size_t)(row0 + c * 8 + rsub) * K + k0 + colE;
                gload_lds16(src, Ab + c * 512);
            } else {
                int c2 = c - 16;
                const unsigned short* src = Bt + (size_t)(col0 + c2 * 8 + rsub) * K + k0 + colE;
                gload_lds16(src, Bb + c2 * 512);
            }
        }
    };

    stage(0, 0);
    __syncthreads();
    int cur = 0;
    const int NT = K / BK;
    for (int t = 0; t < NT; ++t) {
        if (t + 1 < NT) stage(cur ^ 1, (t + 1) * BK);
        const unsigned short* Ab = &lds[cur][0];
        const unsigned short* Bb = &lds[cur][BM * BK];
#pragma unroll
        for (int kk = 0; kk < 2; ++kk) {
            const int cb = ((kk * 64 + g * 16) ^ ((c16 & 7) << 4)) >> 1;
            short8 af[4], bfr[2];
#pragma unroll
            for (int m = 0; m < 4; ++m) {
                int row = wr * 64 + m * 16 + c16;
                af[m] = *(const short8*)(Ab + row * BK + cb);
            }
#pragma unroll
            for (int n = 0; n < 2; ++n) {
                int row = wc * 32 + n * 16 + c16;
                bfr[n] = *(const short8*)(Bb + row * BK + cb);
            }
#pragma unroll
            for (int m = 0; m < 4; ++m)
#pragma unroll
                for (int n = 0; n < 2; ++n)
                    acc[m][n] = mfma16(af[m], bfr[n], acc[m][n]);
        }
        __syncthreads();
        cur ^= 1;
    }

#pragma unroll
    for (int m = 0; m < 4; ++m) {
#pragma unroll
        for (int n = 0; n < 2; ++n) {
            int gc = col0 + wc * 32 + n * 16 + c16;
            float bi = bias[gc];
#pragma unroll
            for (int r = 0; r < 4; ++r) {
                int gr = row0 + wr * 64 + m * 16 + g * 4 + r;
                float v = (acc[m][n][r] + bi) * oscale;
                if (mode == 0) {
                    Cf[(size_t)gr * N + gc] = v;
                } else {
                    int b = gr >> 11, s = gr & (Sc - 1);
                    int h = gc >> 6, d = gc & (Dc - 1);
                    Cb[(((size_t)b * Hc + h) * Sc + s) * Dc + d] = f2bf(v);
                }
            }
        }
    }
}

// ---------------------------------------------------------------------------
// Flash attention v5: swapped QK^T, scores pre-scaled into exp2 domain (Q was
// multiplied by 0.125*log2e in projection), raw v_exp_f32 + v_cvt_pk_bf16_f32,
// compile-time double-buffer pointers, incrementally advanced staging ptrs.
// grid (B*H, S/64); 256 threads = 4 waves; each wave owns 16 q-rows (= c16).
// ---------------------------------------------------------------------------
__global__ __launch_bounds__(256) void attn_mfma_kernel(
    const unsigned short* __restrict__ Q, const unsigned short* __restrict__ K,
    const unsigned short* __restrict__ Vt, unsigned short* __restrict__ Y)
{
    __shared__ __align__(16) unsigned short lds[2][2][64 * 64];  // 32 KB

    const int tid  = threadIdx.x;
    const int lane = tid & 63, wid = tid >> 6;
    const int g = lane >> 4, c16 = lane & 15;
    const int bh = blockIdx.x;
    const int q0 = blockIdx.y * 64;
    const size_t base = (size_t)bh * Sc * Dc;

    // Q as B-frag: lane c16 = q, k elems = d  (Q already scaled by 0.125*log2e)
    const unsigned short* Qp = Q + base + (size_t)(q0 + wid * 16 + c16) * Dc;
    const short8 bq0 = *(const short8*)(Qp + g * 8);
    const short8 bq1 = *(const short8*)(Qp + 32 + g * 8);

    const int rsub = lane >> 3;
    const int srcoffE = 8 * ((lane & 7) ^ rsub);   // swizzled source, in elems
    const int row0g = (wid * 2 + 0) * 8 + rsub;
    const int row1g = (wid * 2 + 1) * 8 + rsub;

    // per-lane global staging pointers, advanced incrementally per tile
    const unsigned short* kg0 = K  + base + (size_t)row0g * Dc + srcoffE;
    const unsigned short* kg1 = K  + base + (size_t)row1g * Dc + srcoffE;
    const unsigned short* vg0 = Vt + base + (size_t)row0g * Sc + srcoffE;
    const unsigned short* vg1 = Vt + base + (size_t)row1g * Sc + srcoffE;

    f32x4 o[4] = {};
    float mrun = -INFINITY, lsum = 0.f;

    auto stage = [&](unsigned short* kbuf, unsigned short* vbuf) {
        gload_lds16(kg0, kbuf + (wid * 2 + 0) * 512);
        gload_lds16(kg1, kbuf + (wid * 2 + 1) * 512);
        gload_lds16(vg0, vbuf + (wid * 2 + 0) * 512);
        gload_lds16(vg1, vbuf + (wid * 2 + 1) * 512);
        kg0 += 64 * Dc; kg1 += 64 * Dc;   // K: next 64 keys
        vg0 += 64;      vg1 += 64;        // Vt: next 64 keys along S
    };

    const int sw = (c16 & 7) << 4;

    auto tile = [&](const unsigned short* kbuf, const unsigned short* vbuf,
                    unsigned short* nkbuf, unsigned short* nvbuf, bool doStage) {
        if (doStage) stage(nkbuf, nvbuf);
        const char* kbc = (const char*)kbuf;
        const char* vbc = (const char*)vbuf;

        // QK^T: 4 column tiles of 16 keys, K-dim 64 = 2 MFMAs each
        f32x4 c[4];
        __builtin_amdgcn_s_setprio(1);
#pragma unroll
        for (int ct = 0; ct < 4; ++ct) {
            const int kr = ct * 16 + c16;
            short8 alo = *(const short8*)(kbc + kr * 128 + ((16 * g) ^ sw));
            short8 ahi = *(const short8*)(kbc + kr * 128 + ((64 + 16 * g) ^ sw));
            f32x4 z = {};
            z = mfma16(alo, bq0, z);
            c[ct] = mfma16(ahi, bq1, z);
        }
        __builtin_amdgcn_s_setprio(0);

        // softmax over 64 keys, log2 domain; depth-4 max tree (v_max3-friendly)
        float t0 = fmaxf(fmaxf(c[0][0], c[0][1]), fmaxf(c[0][2], c[0][3]));
        float t1 = fmaxf(fmaxf(c[1][0], c[1][1]), fmaxf(c[1][2], c[1][3]));
        float t2 = fmaxf(fmaxf(c[2][0], c[2][1]), fmaxf(c[2][2], c[2][3]));
        float t3 = fmaxf(fmaxf(c[3][0], c[3][1]), fmaxf(c[3][2], c[3][3]));
        float tm = fmaxf(fmaxf(t0, t1), fmaxf(t2, t3));
        tm = fmaxf(tm, __shfl_xor(tm, 16));
        tm = fmaxf(tm, __shfl_xor(tm, 32));
        // defer-max: rescale only when max grew by > 8 (p bounded by 2^8)
        if (!__all(tm <= mrun + 8.0f)) {
            float mnew = fmaxf(mrun, tm);
            float corr = exp2_fast(mrun - mnew);
            lsum *= corr;
#pragma unroll
            for (int dt = 0; dt < 4; ++dt)
#pragma unroll
                for (int r = 0; r < 4; ++r) o[dt][r] *= corr;
            mrun = mnew;
        }
        float ps = 0.f;
        short4v pbv[4];
#pragma unroll
        for (int ct = 0; ct < 4; ++ct) {
            float p0 = exp2_fast(c[ct][0] - mrun);
            float p1 = exp2_fast(c[ct][1] - mrun);
            float p2 = exp2_fast(c[ct][2] - mrun);
            float p3 = exp2_fast(c[ct][3] - mrun);
            ps += (p0 + p1) + (p2 + p3);
            int2v w;
            w[0] = cvt_pk_bf16(p0, p1);
            w[1] = cvt_pk_bf16(p2, p3);
            pbv[ct] = __builtin_bit_cast(short4v, w);
        }
        ps += __shfl_xor(ps, 16);
        ps += __shfl_xor(ps, 32);
        lsum += ps;

        // PV: A = V-tile (rows=d), B = P (in-register), k=16 per ct
        __builtin_amdgcn_s_setprio(1);
#pragma unroll
        for (int dt = 0; dt < 4; ++dt) {
            const int drow = dt * 16 + c16;
#pragma unroll
            for (int ct = 0; ct < 4; ++ct) {
                short4v va = *(const short4v*)(vbc + drow * 128 + ((ct * 32 + 8 * g) ^ sw));
                o[dt] = mfma16k16(va, pbv[ct], o[dt]);
            }
        }
        __builtin_amdgcn_s_setprio(0);
        __syncthreads();
    };

    unsigned short* k0b = &lds[0][0][0]; unsigned short* v0b = &lds[0][1][0];
    unsigned short* k1b = &lds[1][0][0]; unsigned short* v1b = &lds[1][1][0];

    stage(k0b, v0b);
    __syncthreads();
    for (int kt = 0; kt < Sc / 64 - 2; kt += 2) {
        tile(k0b, v0b, k1b, v1b, true);
        tile(k1b, v1b, k0b, v0b, true);
    }
    tile(k0b, v0b, k1b, v1b, true);
    tile(k1b, v1b, nullptr, nullptr, false);

    // epilogue: lane holds O[q=c16][d=dt*16+g*4+r]
    const int b = bh >> 4, h = bh & (Hc - 1);
    const int qg = q0 + wid * 16 + c16;
    unsigned short* yrow = Y + ((size_t)b * Sc + qg) * Ec + h * Dc;
    const float inv = 1.f / lsum;
#pragma unroll
    for (int dt = 0; dt < 4; ++dt)
#pragma unroll
        for (int r = 0; r < 4; ++r)
            yrow[dt * 16 + g * 4 + r] = f2bf(o[dt][r] * inv);
}

// ---------------------------------------------------------------------------
// LayerNorm, torch semantics: (x - mean)/(std + eps)*gain + beta, ddof=1.
// ---------------------------------------------------------------------------
__global__ __launch_bounds__(256) void ln_kernel(
    const float* __restrict__ Z, const float* __restrict__ gain,
    const float* __restrict__ beta, float* __restrict__ out)
{
    __shared__ float red0[4];
    __shared__ float red1[4];
    const int row = blockIdx.x;
    const int t = threadIdx.x;
    const float4* z4 = (const float4*)(Z + (size_t)row * Ec);
    float4 v = z4[t];

    float s = v.x + v.y + v.z + v.w;
#pragma unroll
    for (int off = 32; off > 0; off >>= 1) s += __shfl_down(s, off);
    if ((t & 63) == 0) red0[t >> 6] = s;
    __syncthreads();
    float mean = (red0[0] + red0[1] + red0[2] + red0[3]) * (1.0f / Ec);

    float dx = v.x - mean; float vs = dx * dx;
    dx = v.y - mean; vs += dx * dx;
    dx = v.z - mean; vs += dx * dx;
    dx = v.w - mean; vs += dx * dx;
#pragma unroll
    for (int off = 32; off > 0; off >>= 1) vs += __shfl_down(vs, off);
    if ((t & 63) == 0) red1[t >> 6] = vs;
    __syncthreads();
    float var = (red1[0] + red1[1] + red1[2] + red1[3]) * (1.0f / (Ec - 1));
    float inv = 1.0f / (sqrtf(var) + 1e-6f);

    float4 g = ((const float4*)gain)[t];
    float4 bb = ((const float4*)beta)[t];
    float4 o;
    o.x = (v.x - mean) * inv * g.x + bb.x;
    o.y = (v.y - mean) * inv * g.y + bb.y;
    o.z = (v.z - mean) * inv * g.z + bb.z;
    o.w = (v.w - mean) * inv * g.w + bb.w;
    ((float4*)(out + (size_t)row * Ec))[t] = o;
}

// ---------------------------------------------------------------------------
extern "C" void kernel_launch(void* const* d_in, const int* in_sizes, int n_in,
                              void* d_out, int out_size, void* d_ws, size_t ws_size,
                              hipStream_t stream)
{
    const float* x    = (const float*)d_in[0];
    const float* Wq   = (const float*)d_in[1];
    const float* bq   = (const float*)d_in[2];
    const float* Wk   = (const float*)d_in[3];
    const float* bk   = (const float*)d_in[4];
    const float* Wv   = (const float*)d_in[5];
    const float* bv   = (const float*)d_in[6];
    const float* Wp   = (const float*)d_in[7];
    const float* bp   = (const float*)d_in[8];
    const float* gain = (const float*)d_in[9];
    const float* beta = (const float*)d_in[10];

    const int M = Bc * Sc;                           // 4096
    const size_t MK  = (size_t)M * Ec;               // 4 M elems
    const size_t EE  = (size_t)Ec * Ec;              // 1 M elems

    unsigned short* xb  = (unsigned short*)d_ws;     // [0, 8MB)
    unsigned short* wqt = xb + MK;                   // [8,10)
    unsigned short* wkt = wqt + EE;                  // [10,12)
    unsigned short* wvt = wkt + EE;                  // [12,14)
    unsigned short* wpt = wvt + EE;                  // [14,16)
    unsigned short* qb  = wpt + EE;                  // [16,24)
    unsigned short* kb  = qb + MK;                   // [24,32)
    unsigned short* vb  = kb + MK;                   // [32,40)
    unsigned short* vt  = vb + MK;                   // [40,48)
    unsigned short* yb  = vb;                        // reuse after transpose
    float* z = (float*)qb;                           // fp32, after attn

    const float sl2e = 0.125f * 1.44269504f;         // softmax scale * log2(e)

    convert_x_kernel<<<(int)(MK / 8 / 256), 256, 0, stream>>>(x, xb, (int)(MK / 8));
    transpose_w_kernel<<<dim3(Ec / 64, Ec / 64, 4), 256, 0, stream>>>(
        Wq, Wk, Wv, Wp, wqt, wkt, wvt, wpt);

    dim3 gemm_grid(Ec / BN, M / BM);   // (16, 32)
    gemm_mfma_kernel<<<gemm_grid, 256, 0, stream>>>(xb, wqt, bq, nullptr, qb, M, Ec, Ec, 1, sl2e);
    gemm_mfma_kernel<<<gemm_grid, 256, 0, stream>>>(xb, wkt, bk, nullptr, kb, M, Ec, Ec, 1, 1.0f);
    gemm_mfma_kernel<<<gemm_grid, 256, 0, stream>>>(xb, wvt, bv, nullptr, vb, M, Ec, Ec, 1, 1.0f);

    transpose_v_kernel<<<dim3(Bc * Hc, Sc / 64), 256, 0, stream>>>(vb, vt);

    dim3 attn_grid(Bc * Hc, Sc / 64);
    attn_mfma_kernel<<<attn_grid, 256, 0, stream>>>(qb, kb, vt, yb);

    gemm_mfma_kernel<<<gemm_grid, 256, 0, stream>>>(yb, wpt, bp, z, nullptr, M, Ec, Ec, 0, 1.0f);

    ln_kernel<<<M, 256, 0, stream>>>(z, gain, beta, (float*)d_out);
}

// Round 7
// 155.384 us; speedup vs baseline: 16.7531x; 1.0482x over previous
//
#include <hip/hip_runtime.h>
#include <hip/hip_bf16.h>
#include <math.h>

// Problem constants (fixed by setup_inputs)
constexpr int Bc = 2;
constexpr int Sc = 2048;
constexpr int Ec = 1024;
constexpr int Hc = 16;
constexpr int Dc = 64;

typedef __attribute__((ext_vector_type(8))) short short8;
typedef __attribute__((ext_vector_type(4))) short short4v;
typedef __attribute__((ext_vector_type(2))) int int2v;
typedef __attribute__((ext_vector_type(4))) float f32x4;

__device__ inline unsigned short f2bf(float x) {
    __hip_bfloat16 h = __float2bfloat16(x);
    return *reinterpret_cast<unsigned short*>(&h);
}

__device__ inline f32x4 mfma16(short8 a, short8 b, f32x4 c) {
    return __builtin_amdgcn_mfma_f32_16x16x32_bf16(a, b, c, 0, 0, 0);
}

// 16x16x16 bf16 (k=16): A/B = 4 bf16/lane (k = (lane>>4)*4 + j)
__device__ inline f32x4 mfma16k16(short4v a, short4v b, f32x4 c) {
#if __has_builtin(__builtin_amdgcn_mfma_f32_16x16x16bf16_1k)
    return __builtin_amdgcn_mfma_f32_16x16x16bf16_1k(a, b, c, 0, 0, 0);
#else
    f32x4 d;
    asm("v_mfma_f32_16x16x16_bf16 %0, %1, %2, %3"
        : "=v"(d) : "v"(a), "v"(b), "v"(c));
    return d;
#endif
}

// single-instruction 2^x (pure, schedulable)
__device__ inline float exp2_fast(float x) {
    float r;
    asm("v_exp_f32 %0, %1" : "=v"(r) : "v"(x));
    return r;
}

// pack 2 fp32 -> 2 bf16 in one dword (RNE), one instruction
__device__ inline int cvt_pk_bf16(float lo, float hi) {
    int r;
    asm("v_cvt_pk_bf16_f32 %0, %1, %2" : "=v"(r) : "v"(lo), "v"(hi));
    return r;
}

__device__ inline void gload_lds16(const unsigned short* gsrc, unsigned short* ldst) {
    __builtin_amdgcn_global_load_lds(
        (const __attribute__((address_space(1))) unsigned int*)(const void*)gsrc,
        (__attribute__((address_space(3))) unsigned int*)(void*)ldst,
        16, 0, 0);
}

// ---------------------------------------------------------------------------
// x fp32 [M,K] -> bf16 [M,K]. 8 elems/thread.
// ---------------------------------------------------------------------------
__global__ __launch_bounds__(256) void convert_x_kernel(
    const float* __restrict__ X, unsigned short* __restrict__ Xb, int total8)
{
    int i = blockIdx.x * 256 + threadIdx.x;
    if (i >= total8) return;
    const float4* src = (const float4*)(X + (size_t)i * 8);
    float4 a = src[0], b = src[1];
    short8 o;
    o[0] = f2bf(a.x); o[1] = f2bf(a.y); o[2] = f2bf(a.z); o[3] = f2bf(a.w);
    o[4] = f2bf(b.x); o[5] = f2bf(b.y); o[6] = f2bf(b.z); o[7] = f2bf(b.w);
    *(short8*)(Xb + (size_t)i * 8) = o;
}

// ---------------------------------------------------------------------------
// W fp32 [K,N] -> Wt bf16 [N,K]; blockIdx.z selects which of 4 weights.
// ---------------------------------------------------------------------------
__global__ __launch_bounds__(256) void transpose_w_kernel(
    const float* __restrict__ W0, const float* __restrict__ W1,
    const float* __restrict__ W2, const float* __restrict__ W3,
    unsigned short* __restrict__ T0, unsigned short* __restrict__ T1,
    unsigned short* __restrict__ T2, unsigned short* __restrict__ T3)
{
    __shared__ unsigned short Ls[64][72];
    const float* W; unsigned short* T;
    switch (blockIdx.z) {
        case 0: W = W0; T = T0; break;
        case 1: W = W1; T = T1; break;
        case 2: W = W2; T = T2; break;
        default: W = W3; T = T3; break;
    }
    const int n0 = blockIdx.x * 64, k0 = blockIdx.y * 64;
    const int t = threadIdx.x;
    {
        int k = t >> 2, nb = (t & 3) * 16;
        const float* src = W + (size_t)(k0 + k) * Ec + n0 + nb;
#pragma unroll
        for (int j = 0; j < 16; ++j) Ls[k][nb + j] = f2bf(src[j]);
    }
    __syncthreads();
    {
        int n = t >> 2, kb = (t & 3) * 16;
        short8 o0, o1;
#pragma unroll
        for (int j = 0; j < 8; ++j) { o0[j] = Ls[kb + j][n]; o1[j] = Ls[kb + 8 + j][n]; }
        unsigned short* dst = T + (size_t)(n0 + n) * Ec + k0 + kb;
        *(short8*)dst = o0;
        *(short8*)(dst + 8) = o1;
    }
}

// ---------------------------------------------------------------------------
// bf16 MFMA GEMM: C = (A[M,K]bf16 @ Bt[N,K]bf16^T + bias) * oscale.
// mode 0: fp32 [M,N].
// mode 1: bf16 [B,H,S,D] head scatter.
// mode 2: bf16 [B*H, D, S] transposed head layout (packed 4-s stores).
// ---------------------------------------------------------------------------
constexpr int BM = 128, BN = 64, BK = 64;

__global__ __launch_bounds__(256) void gemm_mfma_kernel(
    const unsigned short* __restrict__ A, const unsigned short* __restrict__ Bt,
    const float* __restrict__ bias, float* __restrict__ Cf,
    unsigned short* __restrict__ Cb, int M, int N, int K, int mode, float oscale)
{
    __shared__ unsigned short lds[2][BM * BK + BN * BK];   // 48 KB
    const int tid = threadIdx.x, lane = tid & 63, wid = tid >> 6;
    const int c16 = lane & 15, g = lane >> 4;
    const int wr = wid >> 1, wc = wid & 1;
    const int row0 = blockIdx.y * BM, col0 = blockIdx.x * BN;

    const int rsub = lane >> 3;
    const int colE = ((lane & 7) ^ rsub) * 8;

    f32x4 acc[4][2] = {};

    auto stage = [&](int buf, int k0) {
        unsigned short* Ab = &lds[buf][0];
        unsigned short* Bb = &lds[buf][BM * BK];
#pragma unroll
        for (int i = 0; i < 6; ++i) {
            int c = wid * 6 + i;
            if (c < 16) {
                const unsigned short* src = A + (size_t)(row0 + c * 8 + rsub) * K + k0 + colE;
                gload_lds16(src, Ab + c * 512);
            } else {
                int c2 = c - 16;
                const unsigned short* src = Bt + (size_t)(col0 + c2 * 8 + rsub) * K + k0 + colE;
                gload_lds16(src, Bb + c2 * 512);
            }
        }
    };

    stage(0, 0);
    __syncthreads();
    int cur = 0;
    const int NT = K / BK;
    for (int t = 0; t < NT; ++t) {
        if (t + 1 < NT) stage(cur ^ 1, (t + 1) * BK);
        const unsigned short* Ab = &lds[cur][0];
        const unsigned short* Bb = &lds[cur][BM * BK];
#pragma unroll
        for (int kk = 0; kk < 2; ++kk) {
            const int cb = ((kk * 64 + g * 16) ^ ((c16 & 7) << 4)) >> 1;
            short8 af[4], bfr[2];
#pragma unroll
            for (int m = 0; m < 4; ++m) {
                int row = wr * 64 + m * 16 + c16;
                af[m] = *(const short8*)(Ab + row * BK + cb);
            }
#pragma unroll
            for (int n = 0; n < 2; ++n) {
                int row = wc * 32 + n * 16 + c16;
                bfr[n] = *(const short8*)(Bb + row * BK + cb);
            }
#pragma unroll
            for (int m = 0; m < 4; ++m)
#pragma unroll
                for (int n = 0; n < 2; ++n)
                    acc[m][n] = mfma16(af[m], bfr[n], acc[m][n]);
        }
        __syncthreads();
        cur ^= 1;
    }

#pragma unroll
    for (int m = 0; m < 4; ++m) {
#pragma unroll
        for (int n = 0; n < 2; ++n) {
            int gc = col0 + wc * 32 + n * 16 + c16;
            float bi = bias[gc];
            if (mode == 2) {
                // [B*H, D, S]: 4 consecutive s per lane -> one 8B store
                int h = gc >> 6, d = gc & (Dc - 1);
                int s0 = row0 + wr * 64 + m * 16 + g * 4;
                int b = s0 >> 11, s = s0 & (Sc - 1);
                short4v pk;
#pragma unroll
                for (int r = 0; r < 4; ++r)
                    pk[r] = (short)f2bf((acc[m][n][r] + bi) * oscale);
                *(short4v*)&Cb[(((size_t)b * Hc + h) * Dc + d) * Sc + s] = pk;
            } else {
#pragma unroll
                for (int r = 0; r < 4; ++r) {
                    int gr = row0 + wr * 64 + m * 16 + g * 4 + r;
                    float v = (acc[m][n][r] + bi) * oscale;
                    if (mode == 0) {
                        Cf[(size_t)gr * N + gc] = v;
                    } else {
                        int b = gr >> 11, s = gr & (Sc - 1);
                        int h = gc >> 6, d = gc & (Dc - 1);
                        Cb[(((size_t)b * Hc + h) * Sc + s) * Dc + d] = f2bf(v);
                    }
                }
            }
        }
    }
}

// ---------------------------------------------------------------------------
// Flash attention v6: 32 q-rows per wave (two 16-row B-frag groups).
// grid (B*H, S/128); 256 threads = 4 waves; block covers 128 q-rows.
// K A-frags / V A-frags are read from LDS ONCE and reused by both q-groups,
// halving per-q LDS traffic; two independent softmax chains give ILP.
// Q pre-scaled by 0.125*log2e (folded into Q projection); exp2 domain.
// ---------------------------------------------------------------------------
__global__ __launch_bounds__(256) void attn_mfma_kernel(
    const unsigned short* __restrict__ Q, const unsigned short* __restrict__ K,
    const unsigned short* __restrict__ Vt, unsigned short* __restrict__ Y)
{
    __shared__ __align__(16) unsigned short lds[2][2][64 * 64];  // 32 KB

    const int tid  = threadIdx.x;
    const int lane = tid & 63, wid = tid >> 6;
    const int g = lane >> 4, c16 = lane & 15;
    const int bh = blockIdx.x;
    const int qw = blockIdx.y * 128 + wid * 32;     // this wave's 32 q-rows
    const size_t base = (size_t)bh * Sc * Dc;

    // Q B-frags for the two 16-row groups
    short8 bq[2][2];
#pragma unroll
    for (int u = 0; u < 2; ++u) {
        const unsigned short* Qp = Q + base + (size_t)(qw + u * 16 + c16) * Dc;
        bq[u][0] = *(const short8*)(Qp + g * 8);
        bq[u][1] = *(const short8*)(Qp + 32 + g * 8);
    }

    const int rsub = lane >> 3;
    const int srcoffE = 8 * ((lane & 7) ^ rsub);   // swizzled source, in elems
    const int row0g = (wid * 2 + 0) * 8 + rsub;
    const int row1g = (wid * 2 + 1) * 8 + rsub;

    const unsigned short* kg0 = K  + base + (size_t)row0g * Dc + srcoffE;
    const unsigned short* kg1 = K  + base + (size_t)row1g * Dc + srcoffE;
    const unsigned short* vg0 = Vt + base + (size_t)row0g * Sc + srcoffE;
    const unsigned short* vg1 = Vt + base + (size_t)row1g * Sc + srcoffE;

    f32x4 o[2][4] = {};
    float mrun[2] = {-INFINITY, -INFINITY}, lsum[2] = {0.f, 0.f};

    auto stage = [&](unsigned short* kbuf, unsigned short* vbuf) {
        gload_lds16(kg0, kbuf + (wid * 2 + 0) * 512);
        gload_lds16(kg1, kbuf + (wid * 2 + 1) * 512);
        gload_lds16(vg0, vbuf + (wid * 2 + 0) * 512);
        gload_lds16(vg1, vbuf + (wid * 2 + 1) * 512);
        kg0 += 64 * Dc; kg1 += 64 * Dc;
        vg0 += 64;      vg1 += 64;
    };

    const int sw = (c16 & 7) << 4;

    auto tile = [&](const unsigned short* kbuf, const unsigned short* vbuf,
                    unsigned short* nkbuf, unsigned short* nvbuf, bool doStage) {
        if (doStage) stage(nkbuf, nvbuf);
        const char* kbc = (const char*)kbuf;
        const char* vbc = (const char*)vbuf;

        // QK^T: 4 column tiles of 16 keys; K frags reused by both q-groups
        f32x4 c[2][4];
        __builtin_amdgcn_s_setprio(1);
#pragma unroll
        for (int ct = 0; ct < 4; ++ct) {
            const int kr = ct * 16 + c16;
            short8 alo = *(const short8*)(kbc + kr * 128 + ((16 * g) ^ sw));
            short8 ahi = *(const short8*)(kbc + kr * 128 + ((64 + 16 * g) ^ sw));
            f32x4 z0 = {}, z1 = {};
            z0 = mfma16(alo, bq[0][0], z0);
            c[0][ct] = mfma16(ahi, bq[0][1], z0);
            z1 = mfma16(alo, bq[1][0], z1);
            c[1][ct] = mfma16(ahi, bq[1][1], z1);
        }
        __builtin_amdgcn_s_setprio(0);

        // softmax per group (log2 domain), two independent chains
        short4v pbv[2][4];
#pragma unroll
        for (int u = 0; u < 2; ++u) {
            float t0 = fmaxf(fmaxf(c[u][0][0], c[u][0][1]), fmaxf(c[u][0][2], c[u][0][3]));
            float t1 = fmaxf(fmaxf(c[u][1][0], c[u][1][1]), fmaxf(c[u][1][2], c[u][1][3]));
            float t2 = fmaxf(fmaxf(c[u][2][0], c[u][2][1]), fmaxf(c[u][2][2], c[u][2][3]));
            float t3 = fmaxf(fmaxf(c[u][3][0], c[u][3][1]), fmaxf(c[u][3][2], c[u][3][3]));
            float tm = fmaxf(fmaxf(t0, t1), fmaxf(t2, t3));
            tm = fmaxf(tm, __shfl_xor(tm, 16));
            tm = fmaxf(tm, __shfl_xor(tm, 32));
            if (!__all(tm <= mrun[u] + 8.0f)) {
                float mnew = fmaxf(mrun[u], tm);
                float corr = exp2_fast(mrun[u] - mnew);
                lsum[u] *= corr;
#pragma unroll
                for (int dt = 0; dt < 4; ++dt)
#pragma unroll
                    for (int r = 0; r < 4; ++r) o[u][dt][r] *= corr;
                mrun[u] = mnew;
            }
            float ps = 0.f;
#pragma unroll
            for (int ct = 0; ct < 4; ++ct) {
                float p0 = exp2_fast(c[u][ct][0] - mrun[u]);
                float p1 = exp2_fast(c[u][ct][1] - mrun[u]);
                float p2 = exp2_fast(c[u][ct][2] - mrun[u]);
                float p3 = exp2_fast(c[u][ct][3] - mrun[u]);
                ps += (p0 + p1) + (p2 + p3);
                int2v w;
                w[0] = cvt_pk_bf16(p0, p1);
                w[1] = cvt_pk_bf16(p2, p3);
                pbv[u][ct] = __builtin_bit_cast(short4v, w);
            }
            ps += __shfl_xor(ps, 16);
            ps += __shfl_xor(ps, 32);
            lsum[u] += ps;
        }

        // PV: V frags read once, feed both q-groups
        __builtin_amdgcn_s_setprio(1);
#pragma unroll
        for (int dt = 0; dt < 4; ++dt) {
            const int drow = dt * 16 + c16;
#pragma unroll
            for (int ct = 0; ct < 4; ++ct) {
                short4v va = *(const short4v*)(vbc + drow * 128 + ((ct * 32 + 8 * g) ^ sw));
                o[0][dt] = mfma16k16(va, pbv[0][ct], o[0][dt]);
                o[1][dt] = mfma16k16(va, pbv[1][ct], o[1][dt]);
            }
        }
        __builtin_amdgcn_s_setprio(0);
        __syncthreads();
    };

    unsigned short* k0b = &lds[0][0][0]; unsigned short* v0b = &lds[0][1][0];
    unsigned short* k1b = &lds[1][0][0]; unsigned short* v1b = &lds[1][1][0];

    stage(k0b, v0b);
    __syncthreads();
    for (int kt = 0; kt < Sc / 64 - 2; kt += 2) {
        tile(k0b, v0b, k1b, v1b, true);
        tile(k1b, v1b, k0b, v0b, true);
    }
    tile(k0b, v0b, k1b, v1b, true);
    tile(k1b, v1b, nullptr, nullptr, false);

    // epilogue: lane holds O[q = qw+u*16+c16][d = dt*16+g*4+r]
    const int b = bh >> 4, h = bh & (Hc - 1);
#pragma unroll
    for (int u = 0; u < 2; ++u) {
        const int qg = qw + u * 16 + c16;
        unsigned short* yrow = Y + ((size_t)b * Sc + qg) * Ec + h * Dc;
        const float inv = 1.f / lsum[u];
#pragma unroll
        for (int dt = 0; dt < 4; ++dt)
#pragma unroll
            for (int r = 0; r < 4; ++r)
                yrow[dt * 16 + g * 4 + r] = f2bf(o[u][dt][r] * inv);
    }
}

// ---------------------------------------------------------------------------
// LayerNorm, torch semantics: (x - mean)/(std + eps)*gain + beta, ddof=1.
// ---------------------------------------------------------------------------
__global__ __launch_bounds__(256) void ln_kernel(
    const float* __restrict__ Z, const float* __restrict__ gain,
    const float* __restrict__ beta, float* __restrict__ out)
{
    __shared__ float red0[4];
    __shared__ float red1[4];
    const int row = blockIdx.x;
    const int t = threadIdx.x;
    const float4* z4 = (const float4*)(Z + (size_t)row * Ec);
    float4 v = z4[t];

    float s = v.x + v.y + v.z + v.w;
#pragma unroll
    for (int off = 32; off > 0; off >>= 1) s += __shfl_down(s, off);
    if ((t & 63) == 0) red0[t >> 6] = s;
    __syncthreads();
    float mean = (red0[0] + red0[1] + red0[2] + red0[3]) * (1.0f / Ec);

    float dx = v.x - mean; float vs = dx * dx;
    dx = v.y - mean; vs += dx * dx;
    dx = v.z - mean; vs += dx * dx;
    dx = v.w - mean; vs += dx * dx;
#pragma unroll
    for (int off = 32; off > 0; off >>= 1) vs += __shfl_down(vs, off);
    if ((t & 63) == 0) red1[t >> 6] = vs;
    __syncthreads();
    float var = (red1[0] + red1[1] + red1[2] + red1[3]) * (1.0f / (Ec - 1));
    float inv = 1.0f / (sqrtf(var) + 1e-6f);

    float4 g = ((const float4*)gain)[t];
    float4 bb = ((const float4*)beta)[t];
    float4 o;
    o.x = (v.x - mean) * inv * g.x + bb.x;
    o.y = (v.y - mean) * inv * g.y + bb.y;
    o.z = (v.z - mean) * inv * g.z + bb.z;
    o.w = (v.w - mean) * inv * g.w + bb.w;
    ((float4*)(out + (size_t)row * Ec))[t] = o;
}

// ---------------------------------------------------------------------------
extern "C" void kernel_launch(void* const* d_in, const int* in_sizes, int n_in,
                              void* d_out, int out_size, void* d_ws, size_t ws_size,
                              hipStream_t stream)
{
    const float* x    = (const float*)d_in[0];
    const float* Wq   = (const float*)d_in[1];
    const float* bq   = (const float*)d_in[2];
    const float* Wk   = (const float*)d_in[3];
    const float* bk   = (const float*)d_in[4];
    const float* Wv   = (const float*)d_in[5];
    const float* bv   = (const float*)d_in[6];
    const float* Wp   = (const float*)d_in[7];
    const float* bp   = (const float*)d_in[8];
    const float* gain = (const float*)d_in[9];
    const float* beta = (const float*)d_in[10];

    const int M = Bc * Sc;                           // 4096
    const size_t MK  = (size_t)M * Ec;               // 4 M elems
    const size_t EE  = (size_t)Ec * Ec;              // 1 M elems

    unsigned short* xb  = (unsigned short*)d_ws;     // [0, 8MB)
    unsigned short* wqt = xb + MK;                   // [8,10)
    unsigned short* wkt = wqt + EE;                  // [10,12)
    unsigned short* wvt = wkt + EE;                  // [12,14)
    unsigned short* wpt = wvt + EE;                  // [14,16)
    unsigned short* qb  = wpt + EE;                  // [16,24)
    unsigned short* kb  = qb + MK;                   // [24,32)
    unsigned short* vt  = kb + MK;                   // [32,40)  (V transposed, direct)
    unsigned short* yb  = vt + MK;                   // [40,48)
    float* z = (float*)qb;                           // fp32, after attn

    const float sl2e = 0.125f * 1.44269504f;         // softmax scale * log2(e)

    convert_x_kernel<<<(int)(MK / 8 / 256), 256, 0, stream>>>(x, xb, (int)(MK / 8));
    transpose_w_kernel<<<dim3(Ec / 64, Ec / 64, 4), 256, 0, stream>>>(
        Wq, Wk, Wv, Wp, wqt, wkt, wvt, wpt);

    dim3 gemm_grid(Ec / BN, M / BM);   // (16, 32)
    gemm_mfma_kernel<<<gemm_grid, 256, 0, stream>>>(xb, wqt, bq, nullptr, qb, M, Ec, Ec, 1, sl2e);
    gemm_mfma_kernel<<<gemm_grid, 256, 0, stream>>>(xb, wkt, bk, nullptr, kb, M, Ec, Ec, 1, 1.0f);
    gemm_mfma_kernel<<<gemm_grid, 256, 0, stream>>>(xb, wvt, bv, nullptr, vt, M, Ec, Ec, 2, 1.0f);

    dim3 attn_grid(Bc * Hc, Sc / 128);   // (32, 16) = 512 blocks
    attn_mfma_kernel<<<attn_grid, 256, 0, stream>>>(qb, kb, vt, yb);

    gemm_mfma_kernel<<<gemm_grid, 256, 0, stream>>>(yb, wpt, bp, z, nullptr, M, Ec, Ec, 0, 1.0f);

    ln_kernel<<<M, 256, 0, stream>>>(z, gain, beta, (float*)d_out);
}